// Round 1
// baseline (1724.365 us; speedup 1.0000x reference)
//
#include <hip/hip_runtime.h>
#include <hip/hip_bf16.h>
#include <math.h>

// Problem constants (FavorPlusAttention): B=2, T=4096, d=1024, h=16, dk=64, m=256
#define BB 2
#define TT 4096
#define DD 1024
#define NH 16
#define DK 64
#define MM 256
#define BT (BB*TT)        // 8192 rows
#define FEPS 1e-6f

// ---------------------------------------------------------------------------
// GEMM NT: C[M][1024] = scale * (A[M][1024] @ W[1024][1024]^T) (+ bias)
// tile 128x128, BK=16, 256 threads, 8x8 per thread
// ---------------------------------------------------------------------------
__global__ __launch_bounds__(256) void gemm_nt(const float* __restrict__ A,
                                               const float* __restrict__ W,
                                               const float* __restrict__ bias,
                                               float* __restrict__ C,
                                               float scale)
{
    const int tid = threadIdx.x;
    const int tx = tid & 15;        // n-dim, 8 cols each
    const int ty = tid >> 4;        // m-dim, 8 rows each
    const int row0 = blockIdx.y * 128;
    const int col0 = blockIdx.x * 128;

    __shared__ float As[16][132];
    __shared__ float Bs[16][132];

    float acc[8][8];
#pragma unroll
    for (int i = 0; i < 8; i++)
#pragma unroll
        for (int j = 0; j < 8; j++) acc[i][j] = 0.f;

    const float* Ab = A + (size_t)row0 * DD;
    const float* Wb = W + (size_t)col0 * DD;
    const int lr = tid >> 1;            // 0..127
    const int lk = (tid & 1) * 8;       // 0 or 8

    for (int k0 = 0; k0 < DD; k0 += 16) {
        float4 a0 = *(const float4*)(Ab + (size_t)lr * DD + k0 + lk);
        float4 a1 = *(const float4*)(Ab + (size_t)lr * DD + k0 + lk + 4);
        float4 b0 = *(const float4*)(Wb + (size_t)lr * DD + k0 + lk);
        float4 b1 = *(const float4*)(Wb + (size_t)lr * DD + k0 + lk + 4);
        As[lk+0][lr] = a0.x; As[lk+1][lr] = a0.y; As[lk+2][lr] = a0.z; As[lk+3][lr] = a0.w;
        As[lk+4][lr] = a1.x; As[lk+5][lr] = a1.y; As[lk+6][lr] = a1.z; As[lk+7][lr] = a1.w;
        Bs[lk+0][lr] = b0.x; Bs[lk+1][lr] = b0.y; Bs[lk+2][lr] = b0.z; Bs[lk+3][lr] = b0.w;
        Bs[lk+4][lr] = b1.x; Bs[lk+5][lr] = b1.y; Bs[lk+6][lr] = b1.z; Bs[lk+7][lr] = b1.w;
        __syncthreads();
#pragma unroll
        for (int k = 0; k < 16; k++) {
            float a[8], b[8];
            *(float4*)&a[0] = *(const float4*)&As[k][ty * 8];
            *(float4*)&a[4] = *(const float4*)&As[k][ty * 8 + 4];
            *(float4*)&b[0] = *(const float4*)&Bs[k][tx * 8];
            *(float4*)&b[4] = *(const float4*)&Bs[k][tx * 8 + 4];
#pragma unroll
            for (int i = 0; i < 8; i++)
#pragma unroll
                for (int j = 0; j < 8; j++) acc[i][j] += a[i] * b[j];
        }
        __syncthreads();
    }

    float bv[8];
    if (bias) {
        *(float4*)&bv[0] = *(const float4*)(bias + col0 + tx * 8);
        *(float4*)&bv[4] = *(const float4*)(bias + col0 + tx * 8 + 4);
    } else {
#pragma unroll
        for (int j = 0; j < 8; j++) bv[j] = 0.f;
    }
#pragma unroll
    for (int i = 0; i < 8; i++) {
        int r = row0 + ty * 8 + i;
        float* Cr = C + (size_t)r * DD + col0 + tx * 8;
        float o[8];
#pragma unroll
        for (int j = 0; j < 8; j++) o[j] = acc[i][j] * scale + bv[j];
        *(float4*)(Cr)     = *(const float4*)&o[0];
        *(float4*)(Cr + 4) = *(const float4*)&o[4];
    }
}

// ---------------------------------------------------------------------------
// FAVOR+ features: phi[bh][t][m] = (exp(xw - rowmax - 0.5*||x||^2) + EPS)/16
// xw[t][m] = sum_d X[b][t][h*64+d] * proj[h][m][d]
// block: 64 t-rows x 256 m (all of m -> rowmax is block-local). 256 thr, 8x8.
// ---------------------------------------------------------------------------
__global__ __launch_bounds__(256) void favor_kernel(const float* __restrict__ X,
                                                    const float* __restrict__ proj,
                                                    float* __restrict__ phi)
{
    const int bh = blockIdx.y;
    const int b = bh >> 4, h = bh & 15;
    const int t0 = blockIdx.x * 64;
    const int tid = threadIdx.x;
    const int tx = tid & 31;   // m-dim, 8 each -> 256
    const int ty = tid >> 5;   // t-dim, 8 each -> 64

    __shared__ float Xs[16][68];
    __shared__ float Ps[16][260];
    __shared__ float red[64][33];

    float acc[8][8];
    float xn[8];
#pragma unroll
    for (int i = 0; i < 8; i++) {
        xn[i] = 0.f;
#pragma unroll
        for (int j = 0; j < 8; j++) acc[i][j] = 0.f;
    }

    const float* Xb = X + ((size_t)b * TT + t0) * DD + h * DK;
    const float* Pj = proj + (size_t)h * MM * DK;

    for (int k0 = 0; k0 < DK; k0 += 16) {
        {   // X tile: 64 rows x 16 k
            int row = tid >> 2, kq = (tid & 3) << 2;
            float4 v = *(const float4*)(Xb + (size_t)row * DD + k0 + kq);
            Xs[kq+0][row] = v.x; Xs[kq+1][row] = v.y; Xs[kq+2][row] = v.z; Xs[kq+3][row] = v.w;
        }
#pragma unroll
        for (int i = 0; i < 4; i++) {  // proj tile: 256 m x 16 k
            int s = tid + i * 256;
            int mrow = s >> 2, kq = (s & 3) << 2;
            float4 v = *(const float4*)(Pj + (size_t)mrow * DK + k0 + kq);
            Ps[kq+0][mrow] = v.x; Ps[kq+1][mrow] = v.y; Ps[kq+2][mrow] = v.z; Ps[kq+3][mrow] = v.w;
        }
        __syncthreads();
#pragma unroll
        for (int k = 0; k < 16; k++) {
            float a[8], p[8];
            *(float4*)&a[0] = *(const float4*)&Xs[k][ty * 8];
            *(float4*)&a[4] = *(const float4*)&Xs[k][ty * 8 + 4];
            *(float4*)&p[0] = *(const float4*)&Ps[k][tx * 8];
            *(float4*)&p[4] = *(const float4*)&Ps[k][tx * 8 + 4];
#pragma unroll
            for (int i = 0; i < 8; i++) {
                xn[i] += a[i] * a[i];
#pragma unroll
                for (int j = 0; j < 8; j++) acc[i][j] += a[i] * p[j];
            }
        }
        __syncthreads();
    }
    // xn was accumulated 1x per k (redundant across tx, consistent). rowmax:
#pragma unroll
    for (int i = 0; i < 8; i++) {
        float mx = acc[i][0];
#pragma unroll
        for (int j = 1; j < 8; j++) mx = fmaxf(mx, acc[i][j]);
        red[ty * 8 + i][tx] = mx;
    }
    __syncthreads();
    float rmax[8];
#pragma unroll
    for (int i = 0; i < 8; i++) {
        float mx = -3.0e38f;
        for (int jj = 0; jj < 32; jj++) mx = fmaxf(mx, red[ty * 8 + i][jj]);
        rmax[i] = mx;
    }

    float* outp = phi + ((size_t)bh * TT + t0) * MM;
#pragma unroll
    for (int i = 0; i < 8; i++) {
        int r = ty * 8 + i;
        float base = -rmax[i] - 0.5f * xn[i];
        float o[8];
#pragma unroll
        for (int j = 0; j < 8; j++)
            o[j] = (__expf(acc[i][j] + base) + FEPS) * 0.0625f;
        *(float4*)(outp + (size_t)r * MM + tx * 8)     = *(const float4*)&o[0];
        *(float4*)(outp + (size_t)r * MM + tx * 8 + 4) = *(const float4*)&o[4];
    }
}

// ---------------------------------------------------------------------------
// KV partial: KVp[split][bh][m][0..63] = sum_{t in split} phiK[t][m]*V[t][d]
//             KVp[...][64] = sum phiK[t][m]  (Ksum)
// grid (8 splits, 32 bh), 256 threads (thread = m)
// ---------------------------------------------------------------------------
__global__ __launch_bounds__(256) void kv_partial(const float* __restrict__ phiK,
                                                  const float* __restrict__ V,
                                                  float* __restrict__ KVp)
{
    const int split = blockIdx.x, bh = blockIdx.y;
    const int b = bh >> 4, h = bh & 15;
    const int tid = threadIdx.x;  // = m
    __shared__ float Vs[32][68];

    float4 acc4[16];
#pragma unroll
    for (int i = 0; i < 16; i++) acc4[i] = make_float4(0.f, 0.f, 0.f, 0.f);
    float ks = 0.f;

    const float* Vb = V + (size_t)b * TT * DD + h * DK;
    const float* Pb = phiK + (size_t)bh * TT * MM;

    for (int t0 = split * 512; t0 < split * 512 + 512; t0 += 32) {
#pragma unroll
        for (int i = 0; i < 2; i++) {
            int s = tid + i * 256;          // 512 float4 slots
            int tr = s >> 4, dq = (s & 15) << 2;
            float4 v = *(const float4*)(Vb + (size_t)(t0 + tr) * DD + dq);
            *(float4*)&Vs[tr][dq] = v;
        }
        __syncthreads();
        for (int t = 0; t < 32; t++) {
            float ph = Pb[(size_t)(t0 + t) * MM + tid];
            ks += ph;
#pragma unroll
            for (int dq = 0; dq < 16; dq++) {
                float4 v = *(const float4*)&Vs[t][dq * 4];
                acc4[dq].x += ph * v.x;
                acc4[dq].y += ph * v.y;
                acc4[dq].z += ph * v.z;
                acc4[dq].w += ph * v.w;
            }
        }
        __syncthreads();
    }
    float* o = KVp + (((size_t)split * 32 + bh) * MM + tid) * 68;
#pragma unroll
    for (int dq = 0; dq < 16; dq++) *(float4*)(o + dq * 4) = acc4[dq];
    o[64] = ks;
}

__global__ __launch_bounds__(256) void kv_reduce(const float* __restrict__ KVp,
                                                 float* __restrict__ KVf)
{
    int idx = blockIdx.x * 256 + threadIdx.x;   // 32*256*68 = 557056 exact
    float s = 0.f;
    for (int sp = 0; sp < 8; sp++) s += KVp[(size_t)sp * 32 * MM * 68 + idx];
    KVf[idx] = s;
}

// ---------------------------------------------------------------------------
// Output heads: merged[b][t][h*64+dd] = (sum_m phiQ[t][m]*KV[m][dd]) / den
// den = sum_m phiQ[t][m]*Ksum[m] + EPS. KV+Ksum in LDS (256x68).
// grid (64 t-chunks, 32 bh), 256 thr: dd = tid&63, tr = tid>>6, 16 passes x 4 rows
// ---------------------------------------------------------------------------
__global__ __launch_bounds__(256) void attn_out(const float* __restrict__ phiQ,
                                                const float* __restrict__ KVf,
                                                float* __restrict__ merged)
{
    const int bh = blockIdx.y, b = bh >> 4, h = bh & 15;
    const int t0 = blockIdx.x * 64;
    const int tid = threadIdx.x, dd = tid & 63, tr = tid >> 6;

    __shared__ float KVs[256][68];   // 69.6 KB
    const float* src = KVf + (size_t)bh * MM * 68;
#pragma unroll
    for (int i = 0; i < 17; i++) {
        int s = tid + i * 256;  // 4352 float4 slots
        ((float4*)&KVs[0][0])[s] = ((const float4*)src)[s];
    }
    __syncthreads();

    const float* Pq = phiQ + ((size_t)bh * TT + t0) * MM;
    float* Mb = merged + ((size_t)b * TT + t0) * DD + h * DK;

    for (int p = 0; p < 16; p++) {
        int t = p * 4 + tr;
        const float* pr = Pq + (size_t)t * MM;
        // den partial: this lane covers m = dd + 64*jm
        float denp = 0.f;
#pragma unroll
        for (int jm = 0; jm < 4; jm++) {
            int mI = dd + jm * 64;
            denp += pr[mI] * KVs[mI][64];
        }
#pragma unroll
        for (int off = 32; off > 0; off >>= 1) denp += __shfl_xor(denp, off, 64);
        float dinv = 1.f / (denp + FEPS);

        float acc = 0.f;
#pragma unroll 4
        for (int m4 = 0; m4 < 64; m4++) {
            float4 q = *(const float4*)(pr + m4 * 4);
            acc += q.x * KVs[m4 * 4 + 0][dd];
            acc += q.y * KVs[m4 * 4 + 1][dd];
            acc += q.z * KVs[m4 * 4 + 2][dd];
            acc += q.w * KVs[m4 * 4 + 3][dd];
        }
        Mb[(size_t)t * DD + dd] = acc * dinv;
    }
}

// ---------------------------------------------------------------------------
extern "C" void kernel_launch(void* const* d_in, const int* in_sizes, int n_in,
                              void* d_out, int out_size, void* d_ws, size_t ws_size,
                              hipStream_t stream)
{
    (void)in_sizes; (void)n_in; (void)out_size; (void)ws_size;
    const float* x    = (const float*)d_in[0];
    const float* Wq   = (const float*)d_in[1];
    const float* Wk   = (const float*)d_in[2];
    const float* Wv   = (const float*)d_in[3];
    const float* Wo   = (const float*)d_in[4];
    const float* bo   = (const float*)d_in[5];
    const float* proj = (const float*)d_in[6];
    float* out = (float*)d_out;

    float* ws  = (float*)d_ws;
    float* Qs  = ws;                          // 8388608 floats
    float* Ks  = Qs + 8388608ull;             // 8388608
    float* Vb  = Ks + 8388608ull;             // 8388608
    float* phi = Vb + 8388608ull;             // 33554432 (reused phiK then phiQ)
    float* KVp = phi + 33554432ull;           // 8*32*256*68 = 4456448
    float* KVf = KVp + 4456448ull;            // 32*256*68 = 557056
    float* merged = Ks;                       // reuse K buffer after phiK consumed

    dim3 gthr(256);
    dim3 ggrid(8, 64);      // N/128 x M/128

    gemm_nt<<<ggrid, gthr, 0, stream>>>(x, Wq, nullptr, Qs, 0.125f);
    gemm_nt<<<ggrid, gthr, 0, stream>>>(x, Wk, nullptr, Ks, 0.125f);
    gemm_nt<<<ggrid, gthr, 0, stream>>>(x, Wv, nullptr, Vb, 1.0f);

    favor_kernel<<<dim3(64, 32), gthr, 0, stream>>>(Ks, proj, phi);      // phiK
    kv_partial <<<dim3(8, 32),  gthr, 0, stream>>>(phi, Vb, KVp);
    kv_reduce  <<<dim3(2176),   gthr, 0, stream>>>(KVp, KVf);
    favor_kernel<<<dim3(64, 32), gthr, 0, stream>>>(Qs, proj, phi);      // phiQ
    attn_out   <<<dim3(64, 32), gthr, 0, stream>>>(phi, KVf, merged);

    gemm_nt<<<ggrid, gthr, 0, stream>>>(merged, Wo, bo, out, 1.0f);
}

// Round 3
// 1419.097 us; speedup vs baseline: 1.2151x; 1.2151x over previous
//
#include <hip/hip_runtime.h>
#include <hip/hip_bf16.h>
#include <math.h>

// Problem constants (FavorPlusAttention): B=2, T=4096, d=1024, h=16, dk=64, m=256
#define BB 2
#define TT 4096
#define DD 1024
#define NH 16
#define DK 64
#define MM 256
#define BT (BB*TT)        // 8192 rows
#define FEPS 1e-6f

// ---------------------------------------------------------------------------
// GEMM NT: C[M][1024] = scale * (A[M][1024] @ W[1024][1024]^T) (+ bias)
// tile 128x128, BK=16, 256 threads, 8x8 per thread
// ---------------------------------------------------------------------------
__global__ __launch_bounds__(256) void gemm_nt(const float* __restrict__ A,
                                               const float* __restrict__ W,
                                               const float* __restrict__ bias,
                                               float* __restrict__ C,
                                               float scale)
{
    const int tid = threadIdx.x;
    const int tx = tid & 15;        // n-dim, 8 cols each
    const int ty = tid >> 4;        // m-dim, 8 rows each
    const int row0 = blockIdx.y * 128;
    const int col0 = blockIdx.x * 128;

    __shared__ float As[16][132];
    __shared__ float Bs[16][132];

    float acc[8][8];
#pragma unroll
    for (int i = 0; i < 8; i++)
#pragma unroll
        for (int j = 0; j < 8; j++) acc[i][j] = 0.f;

    const float* Ab = A + (size_t)row0 * DD;
    const float* Wb = W + (size_t)col0 * DD;
    const int lr = tid >> 1;            // 0..127
    const int lk = (tid & 1) * 8;       // 0 or 8

    for (int k0 = 0; k0 < DD; k0 += 16) {
        float4 a0 = *(const float4*)(Ab + (size_t)lr * DD + k0 + lk);
        float4 a1 = *(const float4*)(Ab + (size_t)lr * DD + k0 + lk + 4);
        float4 b0 = *(const float4*)(Wb + (size_t)lr * DD + k0 + lk);
        float4 b1 = *(const float4*)(Wb + (size_t)lr * DD + k0 + lk + 4);
        As[lk+0][lr] = a0.x; As[lk+1][lr] = a0.y; As[lk+2][lr] = a0.z; As[lk+3][lr] = a0.w;
        As[lk+4][lr] = a1.x; As[lk+5][lr] = a1.y; As[lk+6][lr] = a1.z; As[lk+7][lr] = a1.w;
        Bs[lk+0][lr] = b0.x; Bs[lk+1][lr] = b0.y; Bs[lk+2][lr] = b0.z; Bs[lk+3][lr] = b0.w;
        Bs[lk+4][lr] = b1.x; Bs[lk+5][lr] = b1.y; Bs[lk+6][lr] = b1.z; Bs[lk+7][lr] = b1.w;
        __syncthreads();
#pragma unroll
        for (int k = 0; k < 16; k++) {
            float a[8], b[8];
            *(float4*)&a[0] = *(const float4*)&As[k][ty * 8];
            *(float4*)&a[4] = *(const float4*)&As[k][ty * 8 + 4];
            *(float4*)&b[0] = *(const float4*)&Bs[k][tx * 8];
            *(float4*)&b[4] = *(const float4*)&Bs[k][tx * 8 + 4];
#pragma unroll
            for (int i = 0; i < 8; i++)
#pragma unroll
                for (int j = 0; j < 8; j++) acc[i][j] += a[i] * b[j];
        }
        __syncthreads();
    }

    float bv[8];
    if (bias) {
        *(float4*)&bv[0] = *(const float4*)(bias + col0 + tx * 8);
        *(float4*)&bv[4] = *(const float4*)(bias + col0 + tx * 8 + 4);
    } else {
#pragma unroll
        for (int j = 0; j < 8; j++) bv[j] = 0.f;
    }
#pragma unroll
    for (int i = 0; i < 8; i++) {
        int r = row0 + ty * 8 + i;
        float* Cr = C + (size_t)r * DD + col0 + tx * 8;
        float o[8];
#pragma unroll
        for (int j = 0; j < 8; j++) o[j] = acc[i][j] * scale + bv[j];
        *(float4*)(Cr)     = *(const float4*)&o[0];
        *(float4*)(Cr + 4) = *(const float4*)&o[4];
    }
}

// ---------------------------------------------------------------------------
// FAVOR+ features: phi[bh][t][m] = (exp(xw - rowmax - 0.5*||x||^2) + EPS)/16
// xw[t][m] = sum_d X[b][t][h*64+d] * proj[h][m][d]
// block: 64 t-rows x 256 m (all of m -> rowmax is block-local). 256 thr, 8x8.
// ---------------------------------------------------------------------------
__global__ __launch_bounds__(256) void favor_kernel(const float* __restrict__ X,
                                                    const float* __restrict__ proj,
                                                    float* __restrict__ phi)
{
    const int bh = blockIdx.y;
    const int b = bh >> 4, h = bh & 15;
    const int t0 = blockIdx.x * 64;
    const int tid = threadIdx.x;
    const int tx = tid & 31;   // m-dim, 8 each -> 256
    const int ty = tid >> 5;   // t-dim, 8 each -> 64

    __shared__ float Xs[16][68];
    __shared__ float Ps[16][260];
    __shared__ float red[64][33];

    float acc[8][8];
    float xn[8];
#pragma unroll
    for (int i = 0; i < 8; i++) {
        xn[i] = 0.f;
#pragma unroll
        for (int j = 0; j < 8; j++) acc[i][j] = 0.f;
    }

    const float* Xb = X + ((size_t)b * TT + t0) * DD + h * DK;
    const float* Pj = proj + (size_t)h * MM * DK;

    for (int k0 = 0; k0 < DK; k0 += 16) {
        {   // X tile: 64 rows x 16 k
            int row = tid >> 2, kq = (tid & 3) << 2;
            float4 v = *(const float4*)(Xb + (size_t)row * DD + k0 + kq);
            Xs[kq+0][row] = v.x; Xs[kq+1][row] = v.y; Xs[kq+2][row] = v.z; Xs[kq+3][row] = v.w;
        }
#pragma unroll
        for (int i = 0; i < 4; i++) {  // proj tile: 256 m x 16 k
            int s = tid + i * 256;
            int mrow = s >> 2, kq = (s & 3) << 2;
            float4 v = *(const float4*)(Pj + (size_t)mrow * DK + k0 + kq);
            Ps[kq+0][mrow] = v.x; Ps[kq+1][mrow] = v.y; Ps[kq+2][mrow] = v.z; Ps[kq+3][mrow] = v.w;
        }
        __syncthreads();
#pragma unroll
        for (int k = 0; k < 16; k++) {
            float a[8], p[8];
            *(float4*)&a[0] = *(const float4*)&Xs[k][ty * 8];
            *(float4*)&a[4] = *(const float4*)&Xs[k][ty * 8 + 4];
            *(float4*)&p[0] = *(const float4*)&Ps[k][tx * 8];
            *(float4*)&p[4] = *(const float4*)&Ps[k][tx * 8 + 4];
#pragma unroll
            for (int i = 0; i < 8; i++) {
                xn[i] += a[i] * a[i];
#pragma unroll
                for (int j = 0; j < 8; j++) acc[i][j] += a[i] * p[j];
            }
        }
        __syncthreads();
    }
    // xn was accumulated 1x per k (redundant across tx, consistent). rowmax:
#pragma unroll
    for (int i = 0; i < 8; i++) {
        float mx = acc[i][0];
#pragma unroll
        for (int j = 1; j < 8; j++) mx = fmaxf(mx, acc[i][j]);
        red[ty * 8 + i][tx] = mx;
    }
    __syncthreads();
    float rmax[8];
#pragma unroll
    for (int i = 0; i < 8; i++) {
        float mx = -3.0e38f;
        for (int jj = 0; jj < 32; jj++) mx = fmaxf(mx, red[ty * 8 + i][jj]);
        rmax[i] = mx;
    }

    float* outp = phi + ((size_t)bh * TT + t0) * MM;
#pragma unroll
    for (int i = 0; i < 8; i++) {
        int r = ty * 8 + i;
        float base = -rmax[i] - 0.5f * xn[i];
        float o[8];
#pragma unroll
        for (int j = 0; j < 8; j++)
            o[j] = (__expf(acc[i][j] + base) + FEPS) * 0.0625f;
        *(float4*)(outp + (size_t)r * MM + tx * 8)     = *(const float4*)&o[0];
        *(float4*)(outp + (size_t)r * MM + tx * 8 + 4) = *(const float4*)&o[4];
    }
}

// ---------------------------------------------------------------------------
// KV partial as a tiled GEMM (rewrite v2): per block a [64 m x 64 dk] tile
// over a 512-long t-chunk. BK=32. KVp[split][bh][m][0..63], Ksum in col 64.
// grid x = 4 m-tiles * 8 splits = 32, grid y = 32 bh -> 1024 blocks.
// 256 threads: tx = dk quad (16), ty = m quad (16); 4x4 acc per thread.
// ---------------------------------------------------------------------------
__global__ __launch_bounds__(256) void kv_partial(const float* __restrict__ phiK,
                                                  const float* __restrict__ V,
                                                  float* __restrict__ KVp)
{
    const int bh = blockIdx.y;
    const int b = bh >> 4, h = bh & 15;
    const int mt = blockIdx.x & 3;          // m-tile (64 wide)
    const int split = blockIdx.x >> 2;      // 0..7, 512 t each
    const int m0 = mt * 64;
    const int tid = threadIdx.x;
    const int tx = tid & 15;    // dk, 4 each
    const int ty = tid >> 4;    // m, 4 each

    __shared__ float Ps[32][68];   // [t][m-col], row stride 272B (16B-aligned)
    __shared__ float Vs[32][68];   // [t][dk]

    float acc[4][4];
#pragma unroll
    for (int i = 0; i < 4; i++)
#pragma unroll
        for (int j = 0; j < 4; j++) acc[i][j] = 0.f;
    float ks0 = 0.f, ks1 = 0.f, ks2 = 0.f, ks3 = 0.f;  // redundant across tx

    const size_t pbase = (size_t)bh * TT * MM + m0;
    const size_t vbase = (size_t)b * TT * DD + h * DK;

    const int lt = tid >> 3;          // 0..31 (t row within chunk)
    const int lc = (tid & 7) * 8;     // 0,8,...,56 (col)

    const int tend = split * 512 + 512;
    for (int t0 = split * 512; t0 < tend; t0 += 32) {
        const float* prow = phiK + pbase + (size_t)(t0 + lt) * MM + lc;
        const float* vrow = V + vbase + (size_t)(t0 + lt) * DD + lc;
        float4 p0 = *(const float4*)(prow);
        float4 p1 = *(const float4*)(prow + 4);
        float4 v0 = *(const float4*)(vrow);
        float4 v1 = *(const float4*)(vrow + 4);
        *(float4*)&Ps[lt][lc]     = p0;
        *(float4*)&Ps[lt][lc + 4] = p1;
        *(float4*)&Vs[lt][lc]     = v0;
        *(float4*)&Vs[lt][lc + 4] = v1;
        __syncthreads();
#pragma unroll
        for (int k = 0; k < 32; k++) {
            float4 a4 = *(const float4*)&Ps[k][ty * 4];
            float4 b4 = *(const float4*)&Vs[k][tx * 4];
            ks0 += a4.x; ks1 += a4.y; ks2 += a4.z; ks3 += a4.w;
            acc[0][0] += a4.x * b4.x; acc[0][1] += a4.x * b4.y;
            acc[0][2] += a4.x * b4.z; acc[0][3] += a4.x * b4.w;
            acc[1][0] += a4.y * b4.x; acc[1][1] += a4.y * b4.y;
            acc[1][2] += a4.y * b4.z; acc[1][3] += a4.y * b4.w;
            acc[2][0] += a4.z * b4.x; acc[2][1] += a4.z * b4.y;
            acc[2][2] += a4.z * b4.z; acc[2][3] += a4.z * b4.w;
            acc[3][0] += a4.w * b4.x; acc[3][1] += a4.w * b4.y;
            acc[3][2] += a4.w * b4.z; acc[3][3] += a4.w * b4.w;
        }
        __syncthreads();
    }

    // KVp row layout: 68 floats per m (cols 65..67 uninitialized, never read)
    float ksv[4] = {ks0, ks1, ks2, ks3};
    float* o = KVp + (((size_t)split * 32 + bh) * MM + m0) * 68;
#pragma unroll
    for (int i = 0; i < 4; i++) {
        float* orow = o + (size_t)(ty * 4 + i) * 68 + tx * 4;
        orow[0] = acc[i][0]; orow[1] = acc[i][1];
        orow[2] = acc[i][2]; orow[3] = acc[i][3];
        if (tx == 0) o[(size_t)(ty * 4 + i) * 68 + 64] = ksv[i];
    }
}

__global__ __launch_bounds__(256) void kv_reduce(const float* __restrict__ KVp,
                                                 float* __restrict__ KVf)
{
    int idx = blockIdx.x * 256 + threadIdx.x;   // 32*256*68 = 557056 exact
    float s = 0.f;
    for (int sp = 0; sp < 8; sp++) s += KVp[(size_t)sp * 32 * MM * 68 + idx];
    KVf[idx] = s;
}

// ---------------------------------------------------------------------------
// Output heads: merged[b][t][h*64+dd] = (sum_m phiQ[t][m]*KV[m][dd]) / den
// den = sum_m phiQ[t][m]*Ksum[m] + EPS. KV+Ksum in LDS (256x68).
// grid (64 t-chunks, 32 bh), 256 thr: dd = tid&63, tr = tid>>6, 16 passes x 4 rows
// ---------------------------------------------------------------------------
__global__ __launch_bounds__(256) void attn_out(const float* __restrict__ phiQ,
                                                const float* __restrict__ KVf,
                                                float* __restrict__ merged)
{
    const int bh = blockIdx.y, b = bh >> 4, h = bh & 15;
    const int t0 = blockIdx.x * 64;
    const int tid = threadIdx.x, dd = tid & 63, tr = tid >> 6;

    __shared__ float KVs[256][68];   // 69.6 KB
    const float* src = KVf + (size_t)bh * MM * 68;
#pragma unroll
    for (int i = 0; i < 17; i++) {
        int s = tid + i * 256;  // 4352 float4 slots
        ((float4*)&KVs[0][0])[s] = ((const float4*)src)[s];
    }
    __syncthreads();

    const float* Pq = phiQ + ((size_t)bh * TT + t0) * MM;
    float* Mb = merged + ((size_t)b * TT + t0) * DD + h * DK;

    for (int p = 0; p < 16; p++) {
        int t = p * 4 + tr;
        const float* pr = Pq + (size_t)t * MM;
        // den partial: this lane covers m = dd + 64*jm
        float denp = 0.f;
#pragma unroll
        for (int jm = 0; jm < 4; jm++) {
            int mI = dd + jm * 64;
            denp += pr[mI] * KVs[mI][64];
        }
#pragma unroll
        for (int off = 32; off > 0; off >>= 1) denp += __shfl_xor(denp, off, 64);
        float dinv = 1.f / (denp + FEPS);

        float acc = 0.f;
#pragma unroll 4
        for (int m4 = 0; m4 < 64; m4++) {
            float4 q = *(const float4*)(pr + m4 * 4);
            acc += q.x * KVs[m4 * 4 + 0][dd];
            acc += q.y * KVs[m4 * 4 + 1][dd];
            acc += q.z * KVs[m4 * 4 + 2][dd];
            acc += q.w * KVs[m4 * 4 + 3][dd];
        }
        Mb[(size_t)t * DD + dd] = acc * dinv;
    }
}

// ---------------------------------------------------------------------------
extern "C" void kernel_launch(void* const* d_in, const int* in_sizes, int n_in,
                              void* d_out, int out_size, void* d_ws, size_t ws_size,
                              hipStream_t stream)
{
    (void)in_sizes; (void)n_in; (void)out_size; (void)ws_size;
    const float* x    = (const float*)d_in[0];
    const float* Wq   = (const float*)d_in[1];
    const float* Wk   = (const float*)d_in[2];
    const float* Wv   = (const float*)d_in[3];
    const float* Wo   = (const float*)d_in[4];
    const float* bo   = (const float*)d_in[5];
    const float* proj = (const float*)d_in[6];
    float* out = (float*)d_out;

    float* ws  = (float*)d_ws;
    float* Qs  = ws;                          // 8388608 floats
    float* Ks  = Qs + 8388608ull;             // 8388608
    float* Vb  = Ks + 8388608ull;             // 8388608
    float* phi = Vb + 8388608ull;             // 33554432 (reused phiK then phiQ)
    float* KVp = phi + 33554432ull;           // 8*32*256*68 = 4456448
    float* KVf = KVp + 4456448ull;            // 32*256*68 = 557056
    float* merged = Ks;                       // reuse K buffer after phiK consumed

    dim3 gthr(256);
    dim3 ggrid(8, 64);      // N/128 x M/128

    gemm_nt<<<ggrid, gthr, 0, stream>>>(x, Wq, nullptr, Qs, 0.125f);
    gemm_nt<<<ggrid, gthr, 0, stream>>>(x, Wk, nullptr, Ks, 0.125f);
    gemm_nt<<<ggrid, gthr, 0, stream>>>(x, Wv, nullptr, Vb, 1.0f);

    favor_kernel<<<dim3(64, 32), gthr, 0, stream>>>(Ks, proj, phi);      // phiK
    kv_partial <<<dim3(32, 32), gthr, 0, stream>>>(phi, Vb, KVp);
    kv_reduce  <<<dim3(2176),   gthr, 0, stream>>>(KVp, KVf);
    favor_kernel<<<dim3(64, 32), gthr, 0, stream>>>(Qs, proj, phi);      // phiQ
    attn_out   <<<dim3(64, 32), gthr, 0, stream>>>(phi, KVf, merged);

    gemm_nt<<<ggrid, gthr, 0, stream>>>(merged, Wo, bo, out, 1.0f);
}

// Round 4
// 1338.944 us; speedup vs baseline: 1.2879x; 1.0599x over previous
//
#include <hip/hip_runtime.h>
#include <hip/hip_bf16.h>
#include <math.h>

// Problem constants (FavorPlusAttention): B=2, T=4096, d=1024, h=16, dk=64, m=256
#define BB 2
#define TT 4096
#define DD 1024
#define NH 16
#define DK 64
#define MM 256
#define BT (BB*TT)        // 8192 rows
#define FEPS 1e-6f

// ---------------------------------------------------------------------------
// GEMM NT: C[M][1024] = scale * (A[M][1024] @ W[1024][1024]^T) (+ bias)
// tile 128x128, BK=16, 256 threads, 8x8 per thread
// ---------------------------------------------------------------------------
__global__ __launch_bounds__(256) void gemm_nt(const float* __restrict__ A,
                                               const float* __restrict__ W,
                                               const float* __restrict__ bias,
                                               float* __restrict__ C,
                                               float scale)
{
    const int tid = threadIdx.x;
    const int tx = tid & 15;        // n-dim, 8 cols each
    const int ty = tid >> 4;        // m-dim, 8 rows each
    const int row0 = blockIdx.y * 128;
    const int col0 = blockIdx.x * 128;

    __shared__ float As[16][132];
    __shared__ float Bs[16][132];

    float acc[8][8];
#pragma unroll
    for (int i = 0; i < 8; i++)
#pragma unroll
        for (int j = 0; j < 8; j++) acc[i][j] = 0.f;

    const float* Ab = A + (size_t)row0 * DD;
    const float* Wb = W + (size_t)col0 * DD;
    const int lr = tid >> 1;            // 0..127
    const int lk = (tid & 1) * 8;       // 0 or 8

    for (int k0 = 0; k0 < DD; k0 += 16) {
        float4 a0 = *(const float4*)(Ab + (size_t)lr * DD + k0 + lk);
        float4 a1 = *(const float4*)(Ab + (size_t)lr * DD + k0 + lk + 4);
        float4 b0 = *(const float4*)(Wb + (size_t)lr * DD + k0 + lk);
        float4 b1 = *(const float4*)(Wb + (size_t)lr * DD + k0 + lk + 4);
        As[lk+0][lr] = a0.x; As[lk+1][lr] = a0.y; As[lk+2][lr] = a0.z; As[lk+3][lr] = a0.w;
        As[lk+4][lr] = a1.x; As[lk+5][lr] = a1.y; As[lk+6][lr] = a1.z; As[lk+7][lr] = a1.w;
        Bs[lk+0][lr] = b0.x; Bs[lk+1][lr] = b0.y; Bs[lk+2][lr] = b0.z; Bs[lk+3][lr] = b0.w;
        Bs[lk+4][lr] = b1.x; Bs[lk+5][lr] = b1.y; Bs[lk+6][lr] = b1.z; Bs[lk+7][lr] = b1.w;
        __syncthreads();
#pragma unroll
        for (int k = 0; k < 16; k++) {
            float a[8], b[8];
            *(float4*)&a[0] = *(const float4*)&As[k][ty * 8];
            *(float4*)&a[4] = *(const float4*)&As[k][ty * 8 + 4];
            *(float4*)&b[0] = *(const float4*)&Bs[k][tx * 8];
            *(float4*)&b[4] = *(const float4*)&Bs[k][tx * 8 + 4];
#pragma unroll
            for (int i = 0; i < 8; i++)
#pragma unroll
                for (int j = 0; j < 8; j++) acc[i][j] += a[i] * b[j];
        }
        __syncthreads();
    }

    float bv[8];
    if (bias) {
        *(float4*)&bv[0] = *(const float4*)(bias + col0 + tx * 8);
        *(float4*)&bv[4] = *(const float4*)(bias + col0 + tx * 8 + 4);
    } else {
#pragma unroll
        for (int j = 0; j < 8; j++) bv[j] = 0.f;
    }
#pragma unroll
    for (int i = 0; i < 8; i++) {
        int r = row0 + ty * 8 + i;
        float* Cr = C + (size_t)r * DD + col0 + tx * 8;
        float o[8];
#pragma unroll
        for (int j = 0; j < 8; j++) o[j] = acc[i][j] * scale + bv[j];
        *(float4*)(Cr)     = *(const float4*)&o[0];
        *(float4*)(Cr + 4) = *(const float4*)&o[4];
    }
}

// ---------------------------------------------------------------------------
// FAVOR+ features: phi[bh][t][m] = (exp(xw - rowmax - 0.5*||x||^2) + EPS)/16
// xw[t][m] = sum_d X[b][t][h*64+d] * proj[h][m][d]
// block: 64 t-rows x 256 m (all of m -> rowmax is block-local). 256 thr, 8x8.
// ---------------------------------------------------------------------------
__global__ __launch_bounds__(256) void favor_kernel(const float* __restrict__ X,
                                                    const float* __restrict__ proj,
                                                    float* __restrict__ phi)
{
    const int bh = blockIdx.y;
    const int b = bh >> 4, h = bh & 15;
    const int t0 = blockIdx.x * 64;
    const int tid = threadIdx.x;
    const int tx = tid & 31;   // m-dim, 8 each -> 256
    const int ty = tid >> 5;   // t-dim, 8 each -> 64

    __shared__ float Xs[16][68];
    __shared__ float Ps[16][260];
    __shared__ float red[64][33];

    float acc[8][8];
    float xn[8];
#pragma unroll
    for (int i = 0; i < 8; i++) {
        xn[i] = 0.f;
#pragma unroll
        for (int j = 0; j < 8; j++) acc[i][j] = 0.f;
    }

    const float* Xb = X + ((size_t)b * TT + t0) * DD + h * DK;
    const float* Pj = proj + (size_t)h * MM * DK;

    for (int k0 = 0; k0 < DK; k0 += 16) {
        {   // X tile: 64 rows x 16 k
            int row = tid >> 2, kq = (tid & 3) << 2;
            float4 v = *(const float4*)(Xb + (size_t)row * DD + k0 + kq);
            Xs[kq+0][row] = v.x; Xs[kq+1][row] = v.y; Xs[kq+2][row] = v.z; Xs[kq+3][row] = v.w;
        }
#pragma unroll
        for (int i = 0; i < 4; i++) {  // proj tile: 256 m x 16 k
            int s = tid + i * 256;
            int mrow = s >> 2, kq = (s & 3) << 2;
            float4 v = *(const float4*)(Pj + (size_t)mrow * DK + k0 + kq);
            Ps[kq+0][mrow] = v.x; Ps[kq+1][mrow] = v.y; Ps[kq+2][mrow] = v.z; Ps[kq+3][mrow] = v.w;
        }
        __syncthreads();
#pragma unroll
        for (int k = 0; k < 16; k++) {
            float a[8], p[8];
            *(float4*)&a[0] = *(const float4*)&Xs[k][ty * 8];
            *(float4*)&a[4] = *(const float4*)&Xs[k][ty * 8 + 4];
            *(float4*)&p[0] = *(const float4*)&Ps[k][tx * 8];
            *(float4*)&p[4] = *(const float4*)&Ps[k][tx * 8 + 4];
#pragma unroll
            for (int i = 0; i < 8; i++) {
                xn[i] += a[i] * a[i];
#pragma unroll
                for (int j = 0; j < 8; j++) acc[i][j] += a[i] * p[j];
            }
        }
        __syncthreads();
    }
    // xn was accumulated 1x per k (redundant across tx, consistent). rowmax:
#pragma unroll
    for (int i = 0; i < 8; i++) {
        float mx = acc[i][0];
#pragma unroll
        for (int j = 1; j < 8; j++) mx = fmaxf(mx, acc[i][j]);
        red[ty * 8 + i][tx] = mx;
    }
    __syncthreads();
    float rmax[8];
#pragma unroll
    for (int i = 0; i < 8; i++) {
        float mx = -3.0e38f;
        for (int jj = 0; jj < 32; jj++) mx = fmaxf(mx, red[ty * 8 + i][jj]);
        rmax[i] = mx;
    }

    float* outp = phi + ((size_t)bh * TT + t0) * MM;
#pragma unroll
    for (int i = 0; i < 8; i++) {
        int r = ty * 8 + i;
        float base = -rmax[i] - 0.5f * xn[i];
        float o[8];
#pragma unroll
        for (int j = 0; j < 8; j++)
            o[j] = (__expf(acc[i][j] + base) + FEPS) * 0.0625f;
        *(float4*)(outp + (size_t)r * MM + tx * 8)     = *(const float4*)&o[0];
        *(float4*)(outp + (size_t)r * MM + tx * 8 + 4) = *(const float4*)&o[4];
    }
}

// ---------------------------------------------------------------------------
// KV partial as a tiled GEMM: per block a [64 m x 64 dk] tile over a 512-long
// t-chunk. BK=32. KVp[split][bh][m][0..63], Ksum in col 64.
// grid x = 4 m-tiles * 8 splits = 32, grid y = 32 bh -> 1024 blocks.
// ---------------------------------------------------------------------------
__global__ __launch_bounds__(256) void kv_partial(const float* __restrict__ phiK,
                                                  const float* __restrict__ V,
                                                  float* __restrict__ KVp)
{
    const int bh = blockIdx.y;
    const int b = bh >> 4, h = bh & 15;
    const int mt = blockIdx.x & 3;          // m-tile (64 wide)
    const int split = blockIdx.x >> 2;      // 0..7, 512 t each
    const int m0 = mt * 64;
    const int tid = threadIdx.x;
    const int tx = tid & 15;    // dk, 4 each
    const int ty = tid >> 4;    // m, 4 each

    __shared__ float Ps[32][68];   // [t][m-col], row stride 272B (16B-aligned)
    __shared__ float Vs[32][68];   // [t][dk]

    float acc[4][4];
#pragma unroll
    for (int i = 0; i < 4; i++)
#pragma unroll
        for (int j = 0; j < 4; j++) acc[i][j] = 0.f;
    float ks0 = 0.f, ks1 = 0.f, ks2 = 0.f, ks3 = 0.f;  // redundant across tx

    const size_t pbase = (size_t)bh * TT * MM + m0;
    const size_t vbase = (size_t)b * TT * DD + h * DK;

    const int lt = tid >> 3;          // 0..31 (t row within chunk)
    const int lc = (tid & 7) * 8;     // 0,8,...,56 (col)

    const int tend = split * 512 + 512;
    for (int t0 = split * 512; t0 < tend; t0 += 32) {
        const float* prow = phiK + pbase + (size_t)(t0 + lt) * MM + lc;
        const float* vrow = V + vbase + (size_t)(t0 + lt) * DD + lc;
        float4 p0 = *(const float4*)(prow);
        float4 p1 = *(const float4*)(prow + 4);
        float4 v0 = *(const float4*)(vrow);
        float4 v1 = *(const float4*)(vrow + 4);
        *(float4*)&Ps[lt][lc]     = p0;
        *(float4*)&Ps[lt][lc + 4] = p1;
        *(float4*)&Vs[lt][lc]     = v0;
        *(float4*)&Vs[lt][lc + 4] = v1;
        __syncthreads();
#pragma unroll
        for (int k = 0; k < 32; k++) {
            float4 a4 = *(const float4*)&Ps[k][ty * 4];
            float4 b4 = *(const float4*)&Vs[k][tx * 4];
            ks0 += a4.x; ks1 += a4.y; ks2 += a4.z; ks3 += a4.w;
            acc[0][0] += a4.x * b4.x; acc[0][1] += a4.x * b4.y;
            acc[0][2] += a4.x * b4.z; acc[0][3] += a4.x * b4.w;
            acc[1][0] += a4.y * b4.x; acc[1][1] += a4.y * b4.y;
            acc[1][2] += a4.y * b4.z; acc[1][3] += a4.y * b4.w;
            acc[2][0] += a4.z * b4.x; acc[2][1] += a4.z * b4.y;
            acc[2][2] += a4.z * b4.z; acc[2][3] += a4.z * b4.w;
            acc[3][0] += a4.w * b4.x; acc[3][1] += a4.w * b4.y;
            acc[3][2] += a4.w * b4.z; acc[3][3] += a4.w * b4.w;
        }
        __syncthreads();
    }

    // KVp row layout: 68 floats per m (cols 65..67 uninitialized, never read)
    float ksv[4] = {ks0, ks1, ks2, ks3};
    float* o = KVp + (((size_t)split * 32 + bh) * MM + m0) * 68;
#pragma unroll
    for (int i = 0; i < 4; i++) {
        float* orow = o + (size_t)(ty * 4 + i) * 68 + tx * 4;
        orow[0] = acc[i][0]; orow[1] = acc[i][1];
        orow[2] = acc[i][2]; orow[3] = acc[i][3];
        if (tx == 0) o[(size_t)(ty * 4 + i) * 68 + 64] = ksv[i];
    }
}

__global__ __launch_bounds__(256) void kv_reduce(const float* __restrict__ KVp,
                                                 float* __restrict__ KVf)
{
    int idx = blockIdx.x * 256 + threadIdx.x;   // 32*256*68 = 557056 exact
    float s = 0.f;
    for (int sp = 0; sp < 8; sp++) s += KVp[(size_t)sp * 32 * MM * 68 + idx];
    KVf[idx] = s;
}

// ---------------------------------------------------------------------------
// Output heads (register-tiled GEMM): per block [128 t x 64 dd] tile of
// num = phiQ @ KV, den = phiQ @ Ksum, out = num/(den+eps).
// K-loop over m in chunks of 64. phiQ staged TRANSPOSED (QsT[m][t], stride
// 132 -> conflict-free b128 a-frag reads); KV chunk + Ksum col in KVc[64][68].
// 256 thr: tx = dd quad (16), ty = t octet (16); acc[8][4] + den[8]/thread.
// grid (32 t-tiles, 32 bh). LDS 51.2 KB -> 3 blocks/CU.
// ---------------------------------------------------------------------------
__global__ __launch_bounds__(256) void attn_out(const float* __restrict__ phiQ,
                                                const float* __restrict__ KVf,
                                                float* __restrict__ merged)
{
    const int bh = blockIdx.y, b = bh >> 4, h = bh & 15;
    const int t0 = blockIdx.x * 128;
    const int tid = threadIdx.x;
    const int tx = tid & 15;      // dd quad
    const int ty = tid >> 4;      // t octet base: rows ty*8 .. ty*8+7

    __shared__ float QsT[64][132];   // 33792 B
    __shared__ float KVc[64][68];    // 17408 B

    float acc[8][4];
    float den[8];
#pragma unroll
    for (int i = 0; i < 8; i++) {
        den[i] = 0.f;
#pragma unroll
        for (int j = 0; j < 4; j++) acc[i][j] = 0.f;
    }

    const float* Pq = phiQ + ((size_t)bh * TT + t0) * MM;
    const float* Kv = KVf + (size_t)bh * MM * 68;

    for (int m0 = 0; m0 < MM; m0 += 64) {
        // stage KV chunk: 64 rows x 16 float4 (+ Ksum col 64)
#pragma unroll
        for (int i = 0; i < 4; i++) {
            int s = tid + i * 256;
            int r = s >> 4, q = (s & 15) * 4;
            *(float4*)&KVc[r][q] = *(const float4*)(Kv + (size_t)(m0 + r) * 68 + q);
        }
        if (tid < 64) KVc[tid][64] = Kv[(size_t)(m0 + tid) * 68 + 64];
        // stage phiQ chunk transposed: 128 t x 64 m -> QsT[m][t]
#pragma unroll
        for (int i = 0; i < 8; i++) {
            int s = tid + i * 256;
            int t = s >> 4, mq = (s & 15) * 4;
            float4 v = *(const float4*)(Pq + (size_t)t * MM + m0 + mq);
            QsT[mq + 0][t] = v.x; QsT[mq + 1][t] = v.y;
            QsT[mq + 2][t] = v.z; QsT[mq + 3][t] = v.w;
        }
        __syncthreads();
#pragma unroll 4
        for (int k = 0; k < 64; k++) {
            float a[8];
            *(float4*)&a[0] = *(const float4*)&QsT[k][ty * 8];
            *(float4*)&a[4] = *(const float4*)&QsT[k][ty * 8 + 4];
            float4 b4 = *(const float4*)&KVc[k][tx * 4];
            float km = KVc[k][64];
#pragma unroll
            for (int i = 0; i < 8; i++) {
                den[i]    += a[i] * km;
                acc[i][0] += a[i] * b4.x;
                acc[i][1] += a[i] * b4.y;
                acc[i][2] += a[i] * b4.z;
                acc[i][3] += a[i] * b4.w;
            }
        }
        __syncthreads();
    }

    float* Mb = merged + ((size_t)b * TT + t0) * DD + h * DK;
#pragma unroll
    for (int i = 0; i < 8; i++) {
        int t = ty * 8 + i;
        float dinv = 1.f / (den[i] + FEPS);
        float o[4];
        o[0] = acc[i][0] * dinv; o[1] = acc[i][1] * dinv;
        o[2] = acc[i][2] * dinv; o[3] = acc[i][3] * dinv;
        *(float4*)(Mb + (size_t)t * DD + tx * 4) = *(const float4*)o;
    }
}

// ---------------------------------------------------------------------------
extern "C" void kernel_launch(void* const* d_in, const int* in_sizes, int n_in,
                              void* d_out, int out_size, void* d_ws, size_t ws_size,
                              hipStream_t stream)
{
    (void)in_sizes; (void)n_in; (void)out_size; (void)ws_size;
    const float* x    = (const float*)d_in[0];
    const float* Wq   = (const float*)d_in[1];
    const float* Wk   = (const float*)d_in[2];
    const float* Wv   = (const float*)d_in[3];
    const float* Wo   = (const float*)d_in[4];
    const float* bo   = (const float*)d_in[5];
    const float* proj = (const float*)d_in[6];
    float* out = (float*)d_out;

    float* ws  = (float*)d_ws;
    float* Qs  = ws;                          // 8388608 floats
    float* Ks  = Qs + 8388608ull;             // 8388608
    float* Vb  = Ks + 8388608ull;             // 8388608
    float* phi = Vb + 8388608ull;             // 33554432 (reused phiK then phiQ)
    float* KVp = phi + 33554432ull;           // 8*32*256*68 = 4456448
    float* KVf = KVp + 4456448ull;            // 32*256*68 = 557056
    float* merged = Ks;                       // reuse K buffer after phiK consumed

    dim3 gthr(256);
    dim3 ggrid(8, 64);      // N/128 x M/128

    gemm_nt<<<ggrid, gthr, 0, stream>>>(x, Wq, nullptr, Qs, 0.125f);
    gemm_nt<<<ggrid, gthr, 0, stream>>>(x, Wk, nullptr, Ks, 0.125f);
    gemm_nt<<<ggrid, gthr, 0, stream>>>(x, Wv, nullptr, Vb, 1.0f);

    favor_kernel<<<dim3(64, 32), gthr, 0, stream>>>(Ks, proj, phi);      // phiK
    kv_partial <<<dim3(32, 32), gthr, 0, stream>>>(phi, Vb, KVp);
    kv_reduce  <<<dim3(2176),   gthr, 0, stream>>>(KVp, KVf);
    favor_kernel<<<dim3(64, 32), gthr, 0, stream>>>(Qs, proj, phi);      // phiQ
    attn_out   <<<dim3(32, 32), gthr, 0, stream>>>(phi, KVf, merged);

    gemm_nt<<<ggrid, gthr, 0, stream>>>(merged, Wo, bo, out, 1.0f);
}

// Round 5
// 695.223 us; speedup vs baseline: 2.4803x; 1.9259x over previous
//
#include <hip/hip_runtime.h>
#include <hip/hip_bf16.h>
#include <math.h>

// Problem constants (FavorPlusAttention): B=2, T=4096, d=1024, h=16, dk=64, m=256
#define BB 2
#define TT 4096
#define DD 1024
#define NH 16
#define DK 64
#define MM 256
#define BT (BB*TT)        // 8192 rows
#define FEPS 1e-6f

using bf16x8 = __attribute__((ext_vector_type(8))) short;
using f32x4  = __attribute__((ext_vector_type(4))) float;

#define GL2LDS16(g, l) __builtin_amdgcn_global_load_lds( \
    (const __attribute__((address_space(1))) void*)(g), \
    (__attribute__((address_space(3))) void*)(l), 16, 0, 0)

// ---------------------------------------------------------------------------
// hi/lo bf16 split: src [rows][1024] fp32 -> dst [rows][2048] bf16 = [hi|lo]
// one block per row, 256 threads x 4 elements
// ---------------------------------------------------------------------------
__global__ __launch_bounds__(256) void split_hl(const float* __restrict__ src,
                                                __hip_bfloat16* __restrict__ dst)
{
    const int r = blockIdx.x;
    const int c = threadIdx.x * 4;
    float4 v = *(const float4*)(src + (size_t)r * 1024 + c);
    float f[4] = {v.x, v.y, v.z, v.w};
    union { __hip_bfloat16 b[4]; uint2 u; } h, l;
#pragma unroll
    for (int i = 0; i < 4; i++) {
        h.b[i] = __float2bfloat16(f[i]);
        l.b[i] = __float2bfloat16(f[i] - __bfloat162float(h.b[i]));
    }
    unsigned short* d = (unsigned short*)dst + (size_t)r * 2048;
    *(uint2*)(d + c)        = h.u;
    *(uint2*)(d + 1024 + c) = l.u;
}

// same, for the 3 QKV weights into one [3][1024][2048] buffer
__global__ __launch_bounds__(256) void split_w3(const float* __restrict__ W0,
                                                const float* __restrict__ W1,
                                                const float* __restrict__ W2,
                                                __hip_bfloat16* __restrict__ dst)
{
    const int r = blockIdx.x;            // 0..3071
    const int wi = r >> 10, rr = r & 1023;
    const float* W = (wi == 0) ? W0 : (wi == 1) ? W1 : W2;
    const int c = threadIdx.x * 4;
    float4 v = *(const float4*)(W + (size_t)rr * 1024 + c);
    float f[4] = {v.x, v.y, v.z, v.w};
    union { __hip_bfloat16 b[4]; uint2 u; } h, l;
#pragma unroll
    for (int i = 0; i < 4; i++) {
        h.b[i] = __float2bfloat16(f[i]);
        l.b[i] = __float2bfloat16(f[i] - __bfloat162float(h.b[i]));
    }
    unsigned short* d = (unsigned short*)dst + (size_t)r * 2048;
    *(uint2*)(d + c)        = h.u;
    *(uint2*)(d + 1024 + c) = l.u;
}

// ---------------------------------------------------------------------------
// Split-bf16 MFMA GEMM (m97 structure): C[row][col] = scale*(A@B^T) (+bias)
// A: [8192][2048] bf16 [hi|lo], B: [1024][2048] bf16 [hi|lo].
// Logical K' = 3072 via segments: seg0 Ahi*Bhi, seg1 Alo*Bhi, seg2 Ahi*Blo.
// 128x128 tile, BK=32, 256 thr = 4 waves, each wave 64x64 via 4x4 of
// 16x16x32 bf16 MFMA. Staging via global_load_lds width=16 (lane-contiguous
// [row][k] LDS layout, no padding). blockIdx.x: which = bx>>3 selects B/C/scale
// (QKV fused); out-GEMM launched with grid.x=8 (which=0) + bias.
// ---------------------------------------------------------------------------
__global__ __launch_bounds__(256) void mfma_gemm3(
    const short* __restrict__ A,
    const short* __restrict__ B0, const short* __restrict__ B1,
    const short* __restrict__ B2,
    float* __restrict__ C0, float* __restrict__ C1, float* __restrict__ C2,
    const float* __restrict__ bias,
    float sc0, float sc1, float sc2)
{
    const int which = blockIdx.x >> 3;
    const int nb = blockIdx.x & 7;
    const int row0 = blockIdx.y * 128;
    const int col0 = nb * 128;
    const short* Bp = (which == 0) ? B0 : (which == 1) ? B1 : B2;
    float* Cp = (which == 0) ? C0 : (which == 1) ? C1 : C2;
    const float scl = (which == 0) ? sc0 : (which == 1) ? sc1 : sc2;

    __shared__ short As[128 * 32];   // 8 KB, [row][k] row-major
    __shared__ short Bs[128 * 32];

    const int tid = threadIdx.x;
    const int w = tid >> 6, lane = tid & 63;
    const int wm = w & 1, wn = w >> 1;

    f32x4 acc[4][4];
#pragma unroll
    for (int i = 0; i < 4; i++)
#pragma unroll
        for (int j = 0; j < 4; j++) acc[i][j] = (f32x4){0.f, 0.f, 0.f, 0.f};

    // staging: 512 slots of 16B per tile; wave w issues slots (w*2+i)*64+lane
    const int sl0 = (w * 2 + 0) * 64 + lane;
    const int sl1 = (w * 2 + 1) * 64 + lane;
    const size_t aoff0 = (size_t)(row0 + (sl0 >> 2)) * 2048 + (sl0 & 3) * 8;
    const size_t aoff1 = (size_t)(row0 + (sl1 >> 2)) * 2048 + (sl1 & 3) * 8;
    const size_t boff0 = (size_t)(col0 + (sl0 >> 2)) * 2048 + (sl0 & 3) * 8;
    const size_t boff1 = (size_t)(col0 + (sl1 >> 2)) * 2048 + (sl1 & 3) * 8;
    short* lA0 = &As[(w * 2 + 0) * 64 * 8];   // wave-uniform LDS bases
    short* lA1 = &As[(w * 2 + 1) * 64 * 8];
    short* lB0 = &Bs[(w * 2 + 0) * 64 * 8];
    short* lB1 = &Bs[(w * 2 + 1) * 64 * 8];

    // fragment read offsets (shorts): [row][k], row = wbase + i*16 + (lane&15)
    const int aFr = (wm * 64 + (lane & 15)) * 32 + (lane >> 4) * 8;
    const int bFr = (wn * 64 + (lane & 15)) * 32 + (lane >> 4) * 8;

    for (int it = 0; it < 96; it++) {
        const int seg = it >> 5;
        const int kk = (it & 31) * 32;
        const int ka = kk + ((seg == 1) ? 1024 : 0);   // A: hi, lo, hi
        const int kb = kk + ((seg == 2) ? 1024 : 0);   // B: hi, hi, lo
        GL2LDS16(A + aoff0 + ka, lA0);
        GL2LDS16(A + aoff1 + ka, lA1);
        GL2LDS16(Bp + boff0 + kb, lB0);
        GL2LDS16(Bp + boff1 + kb, lB1);
        __syncthreads();
        bf16x8 af[4], bfr[4];
#pragma unroll
        for (int i = 0; i < 4; i++) {
            af[i]  = *(const bf16x8*)&As[aFr + i * 512];
            bfr[i] = *(const bf16x8*)&Bs[bFr + i * 512];
        }
#pragma unroll
        for (int i = 0; i < 4; i++)
#pragma unroll
            for (int j = 0; j < 4; j++)
                acc[i][j] = __builtin_amdgcn_mfma_f32_16x16x32_bf16(
                    af[i], bfr[j], acc[i][j], 0, 0, 0);
        __syncthreads();
    }

    // epilogue: C/D layout col = lane&15, row = (lane>>4)*4 + reg  [m89]
    float bv[4];
#pragma unroll
    for (int j = 0; j < 4; j++) {
        int gcol = col0 + wn * 64 + j * 16 + (lane & 15);
        bv[j] = bias ? bias[gcol] : 0.f;
    }
#pragma unroll
    for (int i = 0; i < 4; i++) {
        const int grow = row0 + wm * 64 + i * 16 + (lane >> 4) * 4;
#pragma unroll
        for (int r = 0; r < 4; r++) {
            float* Crow = Cp + (size_t)(grow + r) * 1024;
#pragma unroll
            for (int j = 0; j < 4; j++) {
                int gcol = col0 + wn * 64 + j * 16 + (lane & 15);
                Crow[gcol] = acc[i][j][r] * scl + bv[j];
            }
        }
    }
}

// ---------------------------------------------------------------------------
// FAVOR+ features: phi[bh][t][m] = (exp(xw - rowmax - 0.5*||x||^2) + EPS)/16
// ---------------------------------------------------------------------------
__global__ __launch_bounds__(256) void favor_kernel(const float* __restrict__ X,
                                                    const float* __restrict__ proj,
                                                    float* __restrict__ phi)
{
    const int bh = blockIdx.y;
    const int b = bh >> 4, h = bh & 15;
    const int t0 = blockIdx.x * 64;
    const int tid = threadIdx.x;
    const int tx = tid & 31;   // m-dim, 8 each -> 256
    const int ty = tid >> 5;   // t-dim, 8 each -> 64

    __shared__ float Xs[16][68];
    __shared__ float Ps[16][260];
    __shared__ float red[64][33];

    float acc[8][8];
    float xn[8];
#pragma unroll
    for (int i = 0; i < 8; i++) {
        xn[i] = 0.f;
#pragma unroll
        for (int j = 0; j < 8; j++) acc[i][j] = 0.f;
    }

    const float* Xb = X + ((size_t)b * TT + t0) * DD + h * DK;
    const float* Pj = proj + (size_t)h * MM * DK;

    for (int k0 = 0; k0 < DK; k0 += 16) {
        {   // X tile: 64 rows x 16 k
            int row = tid >> 2, kq = (tid & 3) << 2;
            float4 v = *(const float4*)(Xb + (size_t)row * DD + k0 + kq);
            Xs[kq+0][row] = v.x; Xs[kq+1][row] = v.y; Xs[kq+2][row] = v.z; Xs[kq+3][row] = v.w;
        }
#pragma unroll
        for (int i = 0; i < 4; i++) {  // proj tile: 256 m x 16 k
            int s = tid + i * 256;
            int mrow = s >> 2, kq = (s & 3) << 2;
            float4 v = *(const float4*)(Pj + (size_t)mrow * DK + k0 + kq);
            Ps[kq+0][mrow] = v.x; Ps[kq+1][mrow] = v.y; Ps[kq+2][mrow] = v.z; Ps[kq+3][mrow] = v.w;
        }
        __syncthreads();
#pragma unroll
        for (int k = 0; k < 16; k++) {
            float a[8], p[8];
            *(float4*)&a[0] = *(const float4*)&Xs[k][ty * 8];
            *(float4*)&a[4] = *(const float4*)&Xs[k][ty * 8 + 4];
            *(float4*)&p[0] = *(const float4*)&Ps[k][tx * 8];
            *(float4*)&p[4] = *(const float4*)&Ps[k][tx * 8 + 4];
#pragma unroll
            for (int i = 0; i < 8; i++) {
                xn[i] += a[i] * a[i];
#pragma unroll
                for (int j = 0; j < 8; j++) acc[i][j] += a[i] * p[j];
            }
        }
        __syncthreads();
    }
#pragma unroll
    for (int i = 0; i < 8; i++) {
        float mx = acc[i][0];
#pragma unroll
        for (int j = 1; j < 8; j++) mx = fmaxf(mx, acc[i][j]);
        red[ty * 8 + i][tx] = mx;
    }
    __syncthreads();
    float rmax[8];
#pragma unroll
    for (int i = 0; i < 8; i++) {
        float mx = -3.0e38f;
        for (int jj = 0; jj < 32; jj++) mx = fmaxf(mx, red[ty * 8 + i][jj]);
        rmax[i] = mx;
    }

    float* outp = phi + ((size_t)bh * TT + t0) * MM;
#pragma unroll
    for (int i = 0; i < 8; i++) {
        int r = ty * 8 + i;
        float base = -rmax[i] - 0.5f * xn[i];
        float o[8];
#pragma unroll
        for (int j = 0; j < 8; j++)
            o[j] = (__expf(acc[i][j] + base) + FEPS) * 0.0625f;
        *(float4*)(outp + (size_t)r * MM + tx * 8)     = *(const float4*)&o[0];
        *(float4*)(outp + (size_t)r * MM + tx * 8 + 4) = *(const float4*)&o[4];
    }
}

// ---------------------------------------------------------------------------
// KV partial tiled GEMM: per block [64 m x 64 dk] over a 512-long t-chunk.
// ---------------------------------------------------------------------------
__global__ __launch_bounds__(256) void kv_partial(const float* __restrict__ phiK,
                                                  const float* __restrict__ V,
                                                  float* __restrict__ KVp)
{
    const int bh = blockIdx.y;
    const int b = bh >> 4, h = bh & 15;
    const int mt = blockIdx.x & 3;          // m-tile (64 wide)
    const int split = blockIdx.x >> 2;      // 0..7, 512 t each
    const int m0 = mt * 64;
    const int tid = threadIdx.x;
    const int tx = tid & 15;    // dk, 4 each
    const int ty = tid >> 4;    // m, 4 each

    __shared__ float Ps[32][68];
    __shared__ float Vs[32][68];

    float acc[4][4];
#pragma unroll
    for (int i = 0; i < 4; i++)
#pragma unroll
        for (int j = 0; j < 4; j++) acc[i][j] = 0.f;
    float ks0 = 0.f, ks1 = 0.f, ks2 = 0.f, ks3 = 0.f;

    const size_t pbase = (size_t)bh * TT * MM + m0;
    const size_t vbase = (size_t)b * TT * DD + h * DK;

    const int lt = tid >> 3;
    const int lc = (tid & 7) * 8;

    const int tend = split * 512 + 512;
    for (int t0 = split * 512; t0 < tend; t0 += 32) {
        const float* prow = phiK + pbase + (size_t)(t0 + lt) * MM + lc;
        const float* vrow = V + vbase + (size_t)(t0 + lt) * DD + lc;
        float4 p0 = *(const float4*)(prow);
        float4 p1 = *(const float4*)(prow + 4);
        float4 v0 = *(const float4*)(vrow);
        float4 v1 = *(const float4*)(vrow + 4);
        *(float4*)&Ps[lt][lc]     = p0;
        *(float4*)&Ps[lt][lc + 4] = p1;
        *(float4*)&Vs[lt][lc]     = v0;
        *(float4*)&Vs[lt][lc + 4] = v1;
        __syncthreads();
#pragma unroll
        for (int k = 0; k < 32; k++) {
            float4 a4 = *(const float4*)&Ps[k][ty * 4];
            float4 b4 = *(const float4*)&Vs[k][tx * 4];
            ks0 += a4.x; ks1 += a4.y; ks2 += a4.z; ks3 += a4.w;
            acc[0][0] += a4.x * b4.x; acc[0][1] += a4.x * b4.y;
            acc[0][2] += a4.x * b4.z; acc[0][3] += a4.x * b4.w;
            acc[1][0] += a4.y * b4.x; acc[1][1] += a4.y * b4.y;
            acc[1][2] += a4.y * b4.z; acc[1][3] += a4.y * b4.w;
            acc[2][0] += a4.z * b4.x; acc[2][1] += a4.z * b4.y;
            acc[2][2] += a4.z * b4.z; acc[2][3] += a4.z * b4.w;
            acc[3][0] += a4.w * b4.x; acc[3][1] += a4.w * b4.y;
            acc[3][2] += a4.w * b4.z; acc[3][3] += a4.w * b4.w;
        }
        __syncthreads();
    }

    float ksv[4] = {ks0, ks1, ks2, ks3};
    float* o = KVp + (((size_t)split * 32 + bh) * MM + m0) * 68;
#pragma unroll
    for (int i = 0; i < 4; i++) {
        float* orow = o + (size_t)(ty * 4 + i) * 68 + tx * 4;
        orow[0] = acc[i][0]; orow[1] = acc[i][1];
        orow[2] = acc[i][2]; orow[3] = acc[i][3];
        if (tx == 0) o[(size_t)(ty * 4 + i) * 68 + 64] = ksv[i];
    }
}

__global__ __launch_bounds__(256) void kv_reduce(const float* __restrict__ KVp,
                                                 float* __restrict__ KVf)
{
    int idx = blockIdx.x * 256 + threadIdx.x;   // 32*256*68 = 557056 exact
    float s = 0.f;
    for (int sp = 0; sp < 8; sp++) s += KVp[(size_t)sp * 32 * MM * 68 + idx];
    KVf[idx] = s;
}

// ---------------------------------------------------------------------------
// Output heads (register-tiled GEMM): per block [128 t x 64 dd].
// ---------------------------------------------------------------------------
__global__ __launch_bounds__(256) void attn_out(const float* __restrict__ phiQ,
                                                const float* __restrict__ KVf,
                                                float* __restrict__ merged)
{
    const int bh = blockIdx.y, b = bh >> 4, h = bh & 15;
    const int t0 = blockIdx.x * 128;
    const int tid = threadIdx.x;
    const int tx = tid & 15;      // dd quad
    const int ty = tid >> 4;      // t octet

    __shared__ float QsT[64][132];
    __shared__ float KVc[64][68];

    float acc[8][4];
    float den[8];
#pragma unroll
    for (int i = 0; i < 8; i++) {
        den[i] = 0.f;
#pragma unroll
        for (int j = 0; j < 4; j++) acc[i][j] = 0.f;
    }

    const float* Pq = phiQ + ((size_t)bh * TT + t0) * MM;
    const float* Kv = KVf + (size_t)bh * MM * 68;

    for (int m0 = 0; m0 < MM; m0 += 64) {
#pragma unroll
        for (int i = 0; i < 4; i++) {
            int s = tid + i * 256;
            int r = s >> 4, q = (s & 15) * 4;
            *(float4*)&KVc[r][q] = *(const float4*)(Kv + (size_t)(m0 + r) * 68 + q);
        }
        if (tid < 64) KVc[tid][64] = Kv[(size_t)(m0 + tid) * 68 + 64];
#pragma unroll
        for (int i = 0; i < 8; i++) {
            int s = tid + i * 256;
            int t = s >> 4, mq = (s & 15) * 4;
            float4 v = *(const float4*)(Pq + (size_t)t * MM + m0 + mq);
            QsT[mq + 0][t] = v.x; QsT[mq + 1][t] = v.y;
            QsT[mq + 2][t] = v.z; QsT[mq + 3][t] = v.w;
        }
        __syncthreads();
#pragma unroll 4
        for (int k = 0; k < 64; k++) {
            float a[8];
            *(float4*)&a[0] = *(const float4*)&QsT[k][ty * 8];
            *(float4*)&a[4] = *(const float4*)&QsT[k][ty * 8 + 4];
            float4 b4 = *(const float4*)&KVc[k][tx * 4];
            float km = KVc[k][64];
#pragma unroll
            for (int i = 0; i < 8; i++) {
                den[i]    += a[i] * km;
                acc[i][0] += a[i] * b4.x;
                acc[i][1] += a[i] * b4.y;
                acc[i][2] += a[i] * b4.z;
                acc[i][3] += a[i] * b4.w;
            }
        }
        __syncthreads();
    }

    float* Mb = merged + ((size_t)b * TT + t0) * DD + h * DK;
#pragma unroll
    for (int i = 0; i < 8; i++) {
        int t = ty * 8 + i;
        float dinv = 1.f / (den[i] + FEPS);
        float o[4];
        o[0] = acc[i][0] * dinv; o[1] = acc[i][1] * dinv;
        o[2] = acc[i][2] * dinv; o[3] = acc[i][3] * dinv;
        *(float4*)(Mb + (size_t)t * DD + tx * 4) = *(const float4*)o;
    }
}

// ---------------------------------------------------------------------------
extern "C" void kernel_launch(void* const* d_in, const int* in_sizes, int n_in,
                              void* d_out, int out_size, void* d_ws, size_t ws_size,
                              hipStream_t stream)
{
    (void)in_sizes; (void)n_in; (void)out_size; (void)ws_size;
    const float* x    = (const float*)d_in[0];
    const float* Wq   = (const float*)d_in[1];
    const float* Wk   = (const float*)d_in[2];
    const float* Wv   = (const float*)d_in[3];
    const float* Wo   = (const float*)d_in[4];
    const float* bo   = (const float*)d_in[5];
    const float* proj = (const float*)d_in[6];
    float* out = (float*)d_out;

    float* ws  = (float*)d_ws;
    float* Qs  = ws;                          // 8388608 floats
    float* Ks  = Qs + 8388608ull;             // 8388608
    float* Vb  = Ks + 8388608ull;             // 8388608
    float* phi = Vb + 8388608ull;             // 33554432 (phiK then phiQ)
    float* KVp = phi + 33554432ull;           // 8*32*256*68 = 4456448
    float* KVf = KVp + 4456448ull;            // 32*256*68 = 557056
    float* merged = Ks;                       // reuse K buffer after phiK consumed

    // hi/lo bf16 aliases (lifetime-disjoint with their hosts):
    __hip_bfloat16* x_hl  = (__hip_bfloat16*)phi;  // dead once favor writes phi
    __hip_bfloat16* m_hl  = (__hip_bfloat16*)phi;  // written after phi is dead
    __hip_bfloat16* wqkv  = (__hip_bfloat16*)KVp;  // dead before kv_partial writes
    __hip_bfloat16* wo_hl = (__hip_bfloat16*)Qs;   // written after Qs is dead

    dim3 gthr(256);

    split_w3<<<dim3(3072), gthr, 0, stream>>>(Wq, Wk, Wv, wqkv);
    split_hl<<<dim3(8192), gthr, 0, stream>>>(x, x_hl);
    mfma_gemm3<<<dim3(24, 64), gthr, 0, stream>>>(
        (const short*)x_hl,
        (const short*)wqkv, (const short*)wqkv + 2097152, (const short*)wqkv + 4194304,
        Qs, Ks, Vb, nullptr, 0.125f, 0.125f, 1.0f);

    favor_kernel<<<dim3(64, 32), gthr, 0, stream>>>(Ks, proj, phi);      // phiK
    kv_partial <<<dim3(32, 32), gthr, 0, stream>>>(phi, Vb, KVp);        // clobbers wqkv (dead)
    kv_reduce  <<<dim3(2176),   gthr, 0, stream>>>(KVp, KVf);
    favor_kernel<<<dim3(64, 32), gthr, 0, stream>>>(Qs, proj, phi);      // phiQ (Qs dead after)
    split_hl   <<<dim3(1024),   gthr, 0, stream>>>(Wo, wo_hl);           // into Qs region
    attn_out   <<<dim3(32, 32), gthr, 0, stream>>>(phi, KVf, merged);
    split_hl   <<<dim3(8192),   gthr, 0, stream>>>(merged, m_hl);        // phi dead

    mfma_gemm3<<<dim3(8, 64), gthr, 0, stream>>>(
        (const short*)m_hl,
        (const short*)wo_hl, (const short*)wo_hl, (const short*)wo_hl,
        out, out, out, bo, 1.0f, 1.0f, 1.0f);
}

// Round 6
// 623.145 us; speedup vs baseline: 2.7672x; 1.1157x over previous
//
#include <hip/hip_runtime.h>
#include <hip/hip_bf16.h>
#include <math.h>

// Problem constants (FavorPlusAttention): B=2, T=4096, d=1024, h=16, dk=64, m=256
#define BB 2
#define TT 4096
#define DD 1024
#define NH 16
#define DK 64
#define MM 256
#define BT (BB*TT)        // 8192 rows
#define FEPS 1e-6f

typedef _Float16 f16x8 __attribute__((ext_vector_type(8)));
using f32x4 = __attribute__((ext_vector_type(4))) float;

#define GL2LDS16(g, l) __builtin_amdgcn_global_load_lds( \
    (const __attribute__((address_space(1))) void*)(g), \
    (__attribute__((address_space(3))) void*)(l), 16, 0, 0)

// ---------------------------------------------------------------------------
// hi/lo fp16 split: src [rows][1024] fp32 -> dst [rows][2048] f16 = [hi|lo]
// (lo compensates hi to ~2^-22; A-operand of the split GEMM)
// ---------------------------------------------------------------------------
__global__ __launch_bounds__(256) void split_hl(const float* __restrict__ src,
                                                unsigned short* __restrict__ dst)
{
    const int r = blockIdx.x;
    const int c = threadIdx.x * 4;
    float4 v = *(const float4*)(src + (size_t)r * 1024 + c);
    float f[4] = {v.x, v.y, v.z, v.w};
    union { _Float16 h[4]; uint2 u; } hv, lv;
#pragma unroll
    for (int i = 0; i < 4; i++) {
        hv.h[i] = (_Float16)f[i];
        lv.h[i] = (_Float16)(f[i] - (float)hv.h[i]);
    }
    unsigned short* d = dst + (size_t)r * 2048;
    *(uint2*)(d + c)        = hv.u;
    *(uint2*)(d + 1024 + c) = lv.u;
}

// hi-only fp16 weight cast: 3 weights -> [3][1024][1024] f16 (B-operand).
// Launch with grid=1024 and W0=W1=W2 for a single weight.
__global__ __launch_bounds__(256) void split_w3h(const float* __restrict__ W0,
                                                 const float* __restrict__ W1,
                                                 const float* __restrict__ W2,
                                                 unsigned short* __restrict__ dst)
{
    const int r = blockIdx.x;            // 0..3071
    const int wi = r >> 10, rr = r & 1023;
    const float* W = (wi == 0) ? W0 : (wi == 1) ? W1 : W2;
    const int c = threadIdx.x * 4;
    float4 v = *(const float4*)(W + (size_t)rr * 1024 + c);
    float f[4] = {v.x, v.y, v.z, v.w};
    union { _Float16 h[4]; uint2 u; } hv;
#pragma unroll
    for (int i = 0; i < 4; i++) hv.h[i] = (_Float16)f[i];
    *(uint2*)(dst + (size_t)r * 1024 + c) = hv.u;
}

// ---------------------------------------------------------------------------
// Split-fp16 MFMA GEMM (m97 structure): C = scale*(A@B^T) (+bias)
// A: [8192][2048] f16 [hi|lo] (stride 2048), B: [1024][1024] f16 hi (stride 1024).
// Logical K' = 2048: seg0 Ahi*Bhi, seg1 Alo*Bhi (A*Blo residual ~2^-11 dropped).
// 128x128 tile, BK=32, 256 thr = 4 waves, 4x4 of 16x16x32 f16 MFMA each.
// Staging via global_load_lds width=16, [row][k] LDS layout. QKV fused via
// which = blockIdx.x>>3; out-GEMM uses grid.x=8 (which=0) + bias.
// ---------------------------------------------------------------------------
__global__ __launch_bounds__(256) void mfma_gemm3(
    const unsigned short* __restrict__ A,
    const unsigned short* __restrict__ B0, const unsigned short* __restrict__ B1,
    const unsigned short* __restrict__ B2,
    float* __restrict__ C0, float* __restrict__ C1, float* __restrict__ C2,
    const float* __restrict__ bias,
    float sc0, float sc1, float sc2)
{
    const int which = blockIdx.x >> 3;
    const int nb = blockIdx.x & 7;
    const int row0 = blockIdx.y * 128;
    const int col0 = nb * 128;
    const unsigned short* Bp = (which == 0) ? B0 : (which == 1) ? B1 : B2;
    float* Cp = (which == 0) ? C0 : (which == 1) ? C1 : C2;
    const float scl = (which == 0) ? sc0 : (which == 1) ? sc1 : sc2;

    __shared__ unsigned short As[128 * 32];   // 8 KB, [row][k] row-major
    __shared__ unsigned short Bs[128 * 32];

    const int tid = threadIdx.x;
    const int w = tid >> 6, lane = tid & 63;
    const int wm = w & 1, wn = w >> 1;

    f32x4 acc[4][4];
#pragma unroll
    for (int i = 0; i < 4; i++)
#pragma unroll
        for (int j = 0; j < 4; j++) acc[i][j] = (f32x4){0.f, 0.f, 0.f, 0.f};

    // staging: 512 slots of 16B per tile; wave w issues slots (w*2+i)*64+lane
    const int sl0 = (w * 2 + 0) * 64 + lane;
    const int sl1 = (w * 2 + 1) * 64 + lane;
    const size_t aoff0 = (size_t)(row0 + (sl0 >> 2)) * 2048 + (sl0 & 3) * 8;
    const size_t aoff1 = (size_t)(row0 + (sl1 >> 2)) * 2048 + (sl1 & 3) * 8;
    const size_t boff0 = (size_t)(col0 + (sl0 >> 2)) * 1024 + (sl0 & 3) * 8;
    const size_t boff1 = (size_t)(col0 + (sl1 >> 2)) * 1024 + (sl1 & 3) * 8;
    unsigned short* lA0 = &As[(w * 2 + 0) * 64 * 8];   // wave-uniform LDS bases
    unsigned short* lA1 = &As[(w * 2 + 1) * 64 * 8];
    unsigned short* lB0 = &Bs[(w * 2 + 0) * 64 * 8];
    unsigned short* lB1 = &Bs[(w * 2 + 1) * 64 * 8];

    const int aFr = (wm * 64 + (lane & 15)) * 32 + (lane >> 4) * 8;
    const int bFr = (wn * 64 + (lane & 15)) * 32 + (lane >> 4) * 8;

    for (int it = 0; it < 64; it++) {
        const int kk = (it & 31) * 32;
        const int ka = kk + ((it >> 5) ? 1024 : 0);   // A: hi then lo
        GL2LDS16(A + aoff0 + ka, lA0);
        GL2LDS16(A + aoff1 + ka, lA1);
        GL2LDS16(Bp + boff0 + kk, lB0);
        GL2LDS16(Bp + boff1 + kk, lB1);
        __syncthreads();
        f16x8 af[4], bfr[4];
#pragma unroll
        for (int i = 0; i < 4; i++) {
            af[i]  = *(const f16x8*)&As[aFr + i * 512];
            bfr[i] = *(const f16x8*)&Bs[bFr + i * 512];
        }
#pragma unroll
        for (int i = 0; i < 4; i++)
#pragma unroll
            for (int j = 0; j < 4; j++)
                acc[i][j] = __builtin_amdgcn_mfma_f32_16x16x32_f16(
                    af[i], bfr[j], acc[i][j], 0, 0, 0);
        __syncthreads();
    }

    // epilogue: C/D layout col = lane&15, row = (lane>>4)*4 + reg  [m89]
    float bv[4];
#pragma unroll
    for (int j = 0; j < 4; j++) {
        int gcol = col0 + wn * 64 + j * 16 + (lane & 15);
        bv[j] = bias ? bias[gcol] : 0.f;
    }
#pragma unroll
    for (int i = 0; i < 4; i++) {
        const int grow = row0 + wm * 64 + i * 16 + (lane >> 4) * 4;
#pragma unroll
        for (int r = 0; r < 4; r++) {
            float* Crow = Cp + (size_t)(grow + r) * 1024;
#pragma unroll
            for (int j = 0; j < 4; j++) {
                int gcol = col0 + wn * 64 + j * 16 + (lane & 15);
                Crow[gcol] = acc[i][j][r] * scl + bv[j];
            }
        }
    }
}

// ---------------------------------------------------------------------------
// FAVOR+ features: phi[bh][t][m] = (exp(xw - rowmax - 0.5*||x||^2) + EPS)/16
// ---------------------------------------------------------------------------
__global__ __launch_bounds__(256) void favor_kernel(const float* __restrict__ X,
                                                    const float* __restrict__ proj,
                                                    float* __restrict__ phi)
{
    const int bh = blockIdx.y;
    const int b = bh >> 4, h = bh & 15;
    const int t0 = blockIdx.x * 64;
    const int tid = threadIdx.x;
    const int tx = tid & 31;   // m-dim, 8 each -> 256
    const int ty = tid >> 5;   // t-dim, 8 each -> 64

    __shared__ float Xs[16][68];
    __shared__ float Ps[16][260];
    __shared__ float red[64][33];

    float acc[8][8];
    float xn[8];
#pragma unroll
    for (int i = 0; i < 8; i++) {
        xn[i] = 0.f;
#pragma unroll
        for (int j = 0; j < 8; j++) acc[i][j] = 0.f;
    }

    const float* Xb = X + ((size_t)b * TT + t0) * DD + h * DK;
    const float* Pj = proj + (size_t)h * MM * DK;

    for (int k0 = 0; k0 < DK; k0 += 16) {
        {   // X tile: 64 rows x 16 k
            int row = tid >> 2, kq = (tid & 3) << 2;
            float4 v = *(const float4*)(Xb + (size_t)row * DD + k0 + kq);
            Xs[kq+0][row] = v.x; Xs[kq+1][row] = v.y; Xs[kq+2][row] = v.z; Xs[kq+3][row] = v.w;
        }
#pragma unroll
        for (int i = 0; i < 4; i++) {  // proj tile: 256 m x 16 k
            int s = tid + i * 256;
            int mrow = s >> 2, kq = (s & 3) << 2;
            float4 v = *(const float4*)(Pj + (size_t)mrow * DK + k0 + kq);
            Ps[kq+0][mrow] = v.x; Ps[kq+1][mrow] = v.y; Ps[kq+2][mrow] = v.z; Ps[kq+3][mrow] = v.w;
        }
        __syncthreads();
#pragma unroll
        for (int k = 0; k < 16; k++) {
            float a[8], p[8];
            *(float4*)&a[0] = *(const float4*)&Xs[k][ty * 8];
            *(float4*)&a[4] = *(const float4*)&Xs[k][ty * 8 + 4];
            *(float4*)&p[0] = *(const float4*)&Ps[k][tx * 8];
            *(float4*)&p[4] = *(const float4*)&Ps[k][tx * 8 + 4];
#pragma unroll
            for (int i = 0; i < 8; i++) {
                xn[i] += a[i] * a[i];
#pragma unroll
                for (int j = 0; j < 8; j++) acc[i][j] += a[i] * p[j];
            }
        }
        __syncthreads();
    }
#pragma unroll
    for (int i = 0; i < 8; i++) {
        float mx = acc[i][0];
#pragma unroll
        for (int j = 1; j < 8; j++) mx = fmaxf(mx, acc[i][j]);
        red[ty * 8 + i][tx] = mx;
    }
    __syncthreads();
    float rmax[8];
#pragma unroll
    for (int i = 0; i < 8; i++) {
        float mx = -3.0e38f;
        for (int jj = 0; jj < 32; jj++) mx = fmaxf(mx, red[ty * 8 + i][jj]);
        rmax[i] = mx;
    }

    float* outp = phi + ((size_t)bh * TT + t0) * MM;
#pragma unroll
    for (int i = 0; i < 8; i++) {
        int r = ty * 8 + i;
        float base = -rmax[i] - 0.5f * xn[i];
        float o[8];
#pragma unroll
        for (int j = 0; j < 8; j++)
            o[j] = (__expf(acc[i][j] + base) + FEPS) * 0.0625f;
        *(float4*)(outp + (size_t)r * MM + tx * 8)     = *(const float4*)&o[0];
        *(float4*)(outp + (size_t)r * MM + tx * 8 + 4) = *(const float4*)&o[4];
    }
}

// ---------------------------------------------------------------------------
// KV partial tiled GEMM: per block [64 m x 64 dk] over a 512-long t-chunk.
// ---------------------------------------------------------------------------
__global__ __launch_bounds__(256) void kv_partial(const float* __restrict__ phiK,
                                                  const float* __restrict__ V,
                                                  float* __restrict__ KVp)
{
    const int bh = blockIdx.y;
    const int b = bh >> 4, h = bh & 15;
    const int mt = blockIdx.x & 3;          // m-tile (64 wide)
    const int split = blockIdx.x >> 2;      // 0..7, 512 t each
    const int m0 = mt * 64;
    const int tid = threadIdx.x;
    const int tx = tid & 15;    // dk, 4 each
    const int ty = tid >> 4;    // m, 4 each

    __shared__ float Ps[32][68];
    __shared__ float Vs[32][68];

    float acc[4][4];
#pragma unroll
    for (int i = 0; i < 4; i++)
#pragma unroll
        for (int j = 0; j < 4; j++) acc[i][j] = 0.f;
    float ks0 = 0.f, ks1 = 0.f, ks2 = 0.f, ks3 = 0.f;

    const size_t pbase = (size_t)bh * TT * MM + m0;
    const size_t vbase = (size_t)b * TT * DD + h * DK;

    const int lt = tid >> 3;
    const int lc = (tid & 7) * 8;

    const int tend = split * 512 + 512;
    for (int t0 = split * 512; t0 < tend; t0 += 32) {
        const float* prow = phiK + pbase + (size_t)(t0 + lt) * MM + lc;
        const float* vrow = V + vbase + (size_t)(t0 + lt) * DD + lc;
        float4 p0 = *(const float4*)(prow);
        float4 p1 = *(const float4*)(prow + 4);
        float4 v0 = *(const float4*)(vrow);
        float4 v1 = *(const float4*)(vrow + 4);
        *(float4*)&Ps[lt][lc]     = p0;
        *(float4*)&Ps[lt][lc + 4] = p1;
        *(float4*)&Vs[lt][lc]     = v0;
        *(float4*)&Vs[lt][lc + 4] = v1;
        __syncthreads();
#pragma unroll
        for (int k = 0; k < 32; k++) {
            float4 a4 = *(const float4*)&Ps[k][ty * 4];
            float4 b4 = *(const float4*)&Vs[k][tx * 4];
            ks0 += a4.x; ks1 += a4.y; ks2 += a4.z; ks3 += a4.w;
            acc[0][0] += a4.x * b4.x; acc[0][1] += a4.x * b4.y;
            acc[0][2] += a4.x * b4.z; acc[0][3] += a4.x * b4.w;
            acc[1][0] += a4.y * b4.x; acc[1][1] += a4.y * b4.y;
            acc[1][2] += a4.y * b4.z; acc[1][3] += a4.y * b4.w;
            acc[2][0] += a4.z * b4.x; acc[2][1] += a4.z * b4.y;
            acc[2][2] += a4.z * b4.z; acc[2][3] += a4.z * b4.w;
            acc[3][0] += a4.w * b4.x; acc[3][1] += a4.w * b4.y;
            acc[3][2] += a4.w * b4.z; acc[3][3] += a4.w * b4.w;
        }
        __syncthreads();
    }

    float ksv[4] = {ks0, ks1, ks2, ks3};
    float* o = KVp + (((size_t)split * 32 + bh) * MM + m0) * 68;
#pragma unroll
    for (int i = 0; i < 4; i++) {
        float* orow = o + (size_t)(ty * 4 + i) * 68 + tx * 4;
        orow[0] = acc[i][0]; orow[1] = acc[i][1];
        orow[2] = acc[i][2]; orow[3] = acc[i][3];
        if (tx == 0) o[(size_t)(ty * 4 + i) * 68 + 64] = ksv[i];
    }
}

__global__ __launch_bounds__(256) void kv_reduce(const float* __restrict__ KVp,
                                                 float* __restrict__ KVf)
{
    int idx = blockIdx.x * 256 + threadIdx.x;   // 32*256*68 = 557056 exact
    float s = 0.f;
    for (int sp = 0; sp < 8; sp++) s += KVp[(size_t)sp * 32 * MM * 68 + idx];
    KVf[idx] = s;
}

// ---------------------------------------------------------------------------
// Output heads (register-tiled GEMM): per block [128 t x 64 dd].
// Epilogue writes the hi/lo fp16 split of merged directly: mout[8192][2048],
// hi at col h*64+dd, lo at 1024 + h*64+dd (A-operand of the out GEMM).
// ---------------------------------------------------------------------------
__global__ __launch_bounds__(256) void attn_out(const float* __restrict__ phiQ,
                                                const float* __restrict__ KVf,
                                                unsigned short* __restrict__ mout)
{
    const int bh = blockIdx.y, b = bh >> 4, h = bh & 15;
    const int t0 = blockIdx.x * 128;
    const int tid = threadIdx.x;
    const int tx = tid & 15;      // dd quad
    const int ty = tid >> 4;      // t octet

    __shared__ float QsT[64][132];
    __shared__ float KVc[64][68];

    float acc[8][4];
    float den[8];
#pragma unroll
    for (int i = 0; i < 8; i++) {
        den[i] = 0.f;
#pragma unroll
        for (int j = 0; j < 4; j++) acc[i][j] = 0.f;
    }

    const float* Pq = phiQ + ((size_t)bh * TT + t0) * MM;
    const float* Kv = KVf + (size_t)bh * MM * 68;

    for (int m0 = 0; m0 < MM; m0 += 64) {
#pragma unroll
        for (int i = 0; i < 4; i++) {
            int s = tid + i * 256;
            int r = s >> 4, q = (s & 15) * 4;
            *(float4*)&KVc[r][q] = *(const float4*)(Kv + (size_t)(m0 + r) * 68 + q);
        }
        if (tid < 64) KVc[tid][64] = Kv[(size_t)(m0 + tid) * 68 + 64];
#pragma unroll
        for (int i = 0; i < 8; i++) {
            int s = tid + i * 256;
            int t = s >> 4, mq = (s & 15) * 4;
            float4 v = *(const float4*)(Pq + (size_t)t * MM + m0 + mq);
            QsT[mq + 0][t] = v.x; QsT[mq + 1][t] = v.y;
            QsT[mq + 2][t] = v.z; QsT[mq + 3][t] = v.w;
        }
        __syncthreads();
#pragma unroll 4
        for (int k = 0; k < 64; k++) {
            float a[8];
            *(float4*)&a[0] = *(const float4*)&QsT[k][ty * 8];
            *(float4*)&a[4] = *(const float4*)&QsT[k][ty * 8 + 4];
            float4 b4 = *(const float4*)&KVc[k][tx * 4];
            float km = KVc[k][64];
#pragma unroll
            for (int i = 0; i < 8; i++) {
                den[i]    += a[i] * km;
                acc[i][0] += a[i] * b4.x;
                acc[i][1] += a[i] * b4.y;
                acc[i][2] += a[i] * b4.z;
                acc[i][3] += a[i] * b4.w;
            }
        }
        __syncthreads();
    }

    unsigned short* Mh = mout + ((size_t)b * TT + t0) * 2048 + h * DK;
#pragma unroll
    for (int i = 0; i < 8; i++) {
        int t = ty * 8 + i;
        float dinv = 1.f / (den[i] + FEPS);
        float o[4];
        o[0] = acc[i][0] * dinv; o[1] = acc[i][1] * dinv;
        o[2] = acc[i][2] * dinv; o[3] = acc[i][3] * dinv;
        union { _Float16 h[4]; uint2 u; } hv, lv;
#pragma unroll
        for (int j = 0; j < 4; j++) {
            hv.h[j] = (_Float16)o[j];
            lv.h[j] = (_Float16)(o[j] - (float)hv.h[j]);
        }
        *(uint2*)(Mh + (size_t)t * 2048 + tx * 4)        = hv.u;
        *(uint2*)(Mh + (size_t)t * 2048 + 1024 + tx * 4) = lv.u;
    }
}

// ---------------------------------------------------------------------------
extern "C" void kernel_launch(void* const* d_in, const int* in_sizes, int n_in,
                              void* d_out, int out_size, void* d_ws, size_t ws_size,
                              hipStream_t stream)
{
    (void)in_sizes; (void)n_in; (void)out_size; (void)ws_size;
    const float* x    = (const float*)d_in[0];
    const float* Wq   = (const float*)d_in[1];
    const float* Wk   = (const float*)d_in[2];
    const float* Wv   = (const float*)d_in[3];
    const float* Wo   = (const float*)d_in[4];
    const float* bo   = (const float*)d_in[5];
    const float* proj = (const float*)d_in[6];
    float* out = (float*)d_out;

    float* ws  = (float*)d_ws;
    float* Qs  = ws;                          // 8388608 floats
    float* Ks  = Qs + 8388608ull;             // 8388608
    float* Vb  = Ks + 8388608ull;             // 8388608
    float* phi = Vb + 8388608ull;             // 33554432 (phiK then phiQ)
    float* KVp = phi + 33554432ull;           // 8*32*256*68 = 4456448
    float* KVf = KVp + 4456448ull;            // 32*256*68 = 557056

    // fp16 aliases (lifetime-disjoint with their hosts):
    unsigned short* x_hl = (unsigned short*)phi;  // 32 MB; dead once favor writes phi
    unsigned short* wqkv = (unsigned short*)KVp;  // 6 MB; dead before kv_partial writes
    unsigned short* wo_h = (unsigned short*)Qs;   // 2 MB; written after Qs is dead
    unsigned short* m_hl = (unsigned short*)Ks;   // 32 MB; written after Ks is dead

    dim3 gthr(256);

    split_w3h<<<dim3(3072), gthr, 0, stream>>>(Wq, Wk, Wv, wqkv);
    split_hl <<<dim3(8192), gthr, 0, stream>>>(x, x_hl);
    mfma_gemm3<<<dim3(24, 64), gthr, 0, stream>>>(
        x_hl, wqkv, wqkv + 1048576, wqkv + 2097152,
        Qs, Ks, Vb, nullptr, 0.125f, 0.125f, 1.0f);

    favor_kernel<<<dim3(64, 32), gthr, 0, stream>>>(Ks, proj, phi);      // phiK (clobbers x_hl, dead)
    kv_partial <<<dim3(32, 32), gthr, 0, stream>>>(phi, Vb, KVp);        // clobbers wqkv (dead)
    kv_reduce  <<<dim3(2176),   gthr, 0, stream>>>(KVp, KVf);
    favor_kernel<<<dim3(64, 32), gthr, 0, stream>>>(Qs, proj, phi);      // phiQ (Qs dead after)
    split_w3h  <<<dim3(1024),   gthr, 0, stream>>>(Wo, Wo, Wo, wo_h);    // into Qs region
    attn_out   <<<dim3(32, 32), gthr, 0, stream>>>(phi, KVf, m_hl);      // writes Ks region

    mfma_gemm3<<<dim3(8, 64), gthr, 0, stream>>>(
        m_hl, wo_h, wo_h, wo_h, out, out, out, bo, 1.0f, 1.0f, 1.0f);
}

// Round 8
// 523.298 us; speedup vs baseline: 3.2952x; 1.1908x over previous
//
#include <hip/hip_runtime.h>
#include <hip/hip_bf16.h>
#include <math.h>

// Problem constants (FavorPlusAttention): B=2, T=4096, d=1024, h=16, dk=64, m=256
#define BB 2
#define TT 4096
#define DD 1024
#define NH 16
#define DK 64
#define MM 256
#define BT (BB*TT)        // 8192 rows
#define FEPS 1e-6f

typedef _Float16 f16x8 __attribute__((ext_vector_type(8)));
using f32x4 = __attribute__((ext_vector_type(4))) float;

#define GL2LDS16(g, l) __builtin_amdgcn_global_load_lds( \
    (const __attribute__((address_space(1))) void*)(g), \
    (__attribute__((address_space(3))) void*)(l), 16, 0, 0)

// ---------------------------------------------------------------------------
// hi/lo fp16 split: src [rows][1024] fp32 -> dst [rows][2048] f16 = [hi|lo]
// ---------------------------------------------------------------------------
__global__ __launch_bounds__(256) void split_hl(const float* __restrict__ src,
                                                unsigned short* __restrict__ dst)
{
    const int r = blockIdx.x;
    const int c = threadIdx.x * 4;
    float4 v = *(const float4*)(src + (size_t)r * 1024 + c);
    float f[4] = {v.x, v.y, v.z, v.w};
    union { _Float16 h[4]; uint2 u; } hv, lv;
#pragma unroll
    for (int i = 0; i < 4; i++) {
        hv.h[i] = (_Float16)f[i];
        lv.h[i] = (_Float16)(f[i] - (float)hv.h[i]);
    }
    unsigned short* d = dst + (size_t)r * 2048;
    *(uint2*)(d + c)        = hv.u;
    *(uint2*)(d + 1024 + c) = lv.u;
}

// hi-only fp16 weight cast: 3 weights -> [3][1024][1024] f16 (B-operand).
__global__ __launch_bounds__(256) void split_w3h(const float* __restrict__ W0,
                                                 const float* __restrict__ W1,
                                                 const float* __restrict__ W2,
                                                 unsigned short* __restrict__ dst)
{
    const int r = blockIdx.x;            // 0..3071
    const int wi = r >> 10, rr = r & 1023;
    const float* W = (wi == 0) ? W0 : (wi == 1) ? W1 : W2;
    const int c = threadIdx.x * 4;
    float4 v = *(const float4*)(W + (size_t)rr * 1024 + c);
    float f[4] = {v.x, v.y, v.z, v.w};
    union { _Float16 h[4]; uint2 u; } hv;
#pragma unroll
    for (int i = 0; i < 4; i++) hv.h[i] = (_Float16)f[i];
    *(uint2*)(dst + (size_t)r * 1024 + c) = hv.u;
}

// ---------------------------------------------------------------------------
// Split-fp16 MFMA GEMM (m97 structure): C = scale*(A@B^T) (+bias)
// A: [8192][2048] f16 [hi|lo], B: [1024][1024] f16 hi. K' = 2048 (Ahi*Bhi,
// Alo*Bhi). 128x128 tile, BK=32, 4 waves, 4x4 of 16x16x32 f16 MFMA.
// ---------------------------------------------------------------------------
__global__ __launch_bounds__(256) void mfma_gemm3(
    const unsigned short* __restrict__ A,
    const unsigned short* __restrict__ B0, const unsigned short* __restrict__ B1,
    const unsigned short* __restrict__ B2,
    float* __restrict__ C0, float* __restrict__ C1, float* __restrict__ C2,
    const float* __restrict__ bias,
    float sc0, float sc1, float sc2)
{
    const int which = blockIdx.x >> 3;
    const int nb = blockIdx.x & 7;
    const int row0 = blockIdx.y * 128;
    const int col0 = nb * 128;
    const unsigned short* Bp = (which == 0) ? B0 : (which == 1) ? B1 : B2;
    float* Cp = (which == 0) ? C0 : (which == 1) ? C1 : C2;
    const float scl = (which == 0) ? sc0 : (which == 1) ? sc1 : sc2;

    __shared__ unsigned short As[128 * 32];   // 8 KB, [row][k] row-major
    __shared__ unsigned short Bs[128 * 32];

    const int tid = threadIdx.x;
    const int w = tid >> 6, lane = tid & 63;
    const int wm = w & 1, wn = w >> 1;

    f32x4 acc[4][4];
#pragma unroll
    for (int i = 0; i < 4; i++)
#pragma unroll
        for (int j = 0; j < 4; j++) acc[i][j] = (f32x4){0.f, 0.f, 0.f, 0.f};

    const int sl0 = (w * 2 + 0) * 64 + lane;
    const int sl1 = (w * 2 + 1) * 64 + lane;
    const size_t aoff0 = (size_t)(row0 + (sl0 >> 2)) * 2048 + (sl0 & 3) * 8;
    const size_t aoff1 = (size_t)(row0 + (sl1 >> 2)) * 2048 + (sl1 & 3) * 8;
    const size_t boff0 = (size_t)(col0 + (sl0 >> 2)) * 1024 + (sl0 & 3) * 8;
    const size_t boff1 = (size_t)(col0 + (sl1 >> 2)) * 1024 + (sl1 & 3) * 8;
    unsigned short* lA0 = &As[(w * 2 + 0) * 64 * 8];
    unsigned short* lA1 = &As[(w * 2 + 1) * 64 * 8];
    unsigned short* lB0 = &Bs[(w * 2 + 0) * 64 * 8];
    unsigned short* lB1 = &Bs[(w * 2 + 1) * 64 * 8];

    const int aFr = (wm * 64 + (lane & 15)) * 32 + (lane >> 4) * 8;
    const int bFr = (wn * 64 + (lane & 15)) * 32 + (lane >> 4) * 8;

    for (int it = 0; it < 64; it++) {
        const int kk = (it & 31) * 32;
        const int ka = kk + ((it >> 5) ? 1024 : 0);   // A: hi then lo
        GL2LDS16(A + aoff0 + ka, lA0);
        GL2LDS16(A + aoff1 + ka, lA1);
        GL2LDS16(Bp + boff0 + kk, lB0);
        GL2LDS16(Bp + boff1 + kk, lB1);
        __syncthreads();
        f16x8 af[4], bfr[4];
#pragma unroll
        for (int i = 0; i < 4; i++) {
            af[i]  = *(const f16x8*)&As[aFr + i * 512];
            bfr[i] = *(const f16x8*)&Bs[bFr + i * 512];
        }
#pragma unroll
        for (int i = 0; i < 4; i++)
#pragma unroll
            for (int j = 0; j < 4; j++)
                acc[i][j] = __builtin_amdgcn_mfma_f32_16x16x32_f16(
                    af[i], bfr[j], acc[i][j], 0, 0, 0);
        __syncthreads();
    }

    // epilogue: C/D layout col = lane&15, row = (lane>>4)*4 + reg  [m89]
    float bv[4];
#pragma unroll
    for (int j = 0; j < 4; j++) {
        int gcol = col0 + wn * 64 + j * 16 + (lane & 15);
        bv[j] = bias ? bias[gcol] : 0.f;
    }
#pragma unroll
    for (int i = 0; i < 4; i++) {
        const int grow = row0 + wm * 64 + i * 16 + (lane >> 4) * 4;
#pragma unroll
        for (int r = 0; r < 4; r++) {
            float* Crow = Cp + (size_t)(grow + r) * 1024;
#pragma unroll
            for (int j = 0; j < 4; j++) {
                int gcol = col0 + wn * 64 + j * 16 + (lane & 15);
                Crow[gcol] = acc[i][j][r] * scl + bv[j];
            }
        }
    }
}

// ---------------------------------------------------------------------------
// FAVOR+ features via MFMA: per block one bh, [128 t x 256 m].
// xw = X_head @ proj_head^T as split-fp16 MFMA (K'=128: Xhi*Phi, Xlo*Phi).
// X tile converted to f16 hi/lo in-kernel; proj to f16 hi.
// Wave w owns rows w*32..w*32+32, ALL 256 cols -> rowmax is wave-local
// (reg max over 16 j-tiles + shfl_xor over the 16-lane col group).
// ||x||^2 recomputed from hi+lo (2^-21 rel err). LDS rows padded to 136/72
// shorts (16B-aligned stride, bank offset 4/row -> worst 2-way, free).
// grid (32 t-tiles, 32 bh), 256 threads.
// ---------------------------------------------------------------------------
__global__ __launch_bounds__(256) void favor_mfma(const float* __restrict__ X,
                                                  const float* __restrict__ proj,
                                                  float* __restrict__ phi)
{
    const int bh = blockIdx.y;
    const int b = bh >> 4, h = bh & 15;
    const int t0 = blockIdx.x * 128;
    const int tid = threadIdx.x;
    const int w = tid >> 6, lane = tid & 63;

    __shared__ unsigned short Aq[128 * 136];   // [t][k'], hi 0..63, lo 64..127
    __shared__ unsigned short Bs[256 * 72];    // [m][k] hi only
    __shared__ float xns[128];

    const float* Xb = X + ((size_t)b * TT + t0) * DD + h * DK;
    const float* Pj = proj + (size_t)h * MM * DK;

    // stage X tile: 128 rows x 16 float4 -> hi/lo f16
#pragma unroll
    for (int i = 0; i < 8; i++) {
        int s = tid + i * 256;
        int r = s >> 4, q = (s & 15) * 4;
        float4 v = *(const float4*)(Xb + (size_t)r * DD + q);
        float f[4] = {v.x, v.y, v.z, v.w};
        union { _Float16 h[4]; uint2 u; } hv, lv;
#pragma unroll
        for (int e = 0; e < 4; e++) {
            hv.h[e] = (_Float16)f[e];
            lv.h[e] = (_Float16)(f[e] - (float)hv.h[e]);
        }
        *(uint2*)&Aq[r * 136 + q]      = hv.u;
        *(uint2*)&Aq[r * 136 + 64 + q] = lv.u;
    }
    // stage proj: 256 rows x 16 float4 -> hi f16
#pragma unroll
    for (int i = 0; i < 16; i++) {
        int s = tid + i * 256;
        int r = s >> 4, q = (s & 15) * 4;
        float4 v = *(const float4*)(Pj + (size_t)r * DK + q);
        float f[4] = {v.x, v.y, v.z, v.w};
        union { _Float16 h[4]; uint2 u; } hv;
#pragma unroll
        for (int e = 0; e < 4; e++) hv.h[e] = (_Float16)f[e];
        *(uint2*)&Bs[r * 72 + q] = hv.u;
    }
    __syncthreads();

    // ||x||^2 per row from hi+lo
    if (tid < 128) {
        const unsigned short* ar = &Aq[tid * 136];
        float s = 0.f;
#pragma unroll 8
        for (int k = 0; k < 64; k++) {
            float qv = (float)(*(const _Float16*)&ar[k])
                     + (float)(*(const _Float16*)&ar[64 + k]);
            s += qv * qv;
        }
        xns[tid] = s;
    }

    // MFMA: wave w rows w*32..+32 (2 i-tiles), 16 j-tiles, 4 k-steps
    f32x4 acc[2][16];
#pragma unroll
    for (int i = 0; i < 2; i++)
#pragma unroll
        for (int j = 0; j < 16; j++) acc[i][j] = (f32x4){0.f, 0.f, 0.f, 0.f};

    const int arow0 = (w * 32 + (lane & 15)) * 136 + (lane >> 4) * 8;
    const int brow0 = (lane & 15) * 72 + (lane >> 4) * 8;
#pragma unroll
    for (int ks = 0; ks < 4; ks++) {
        f16x8 a0 = *(const f16x8*)&Aq[arow0 + ks * 32];
        f16x8 a1 = *(const f16x8*)&Aq[arow0 + 16 * 136 + ks * 32];
        const int bko = (ks & 1) * 32;
#pragma unroll
        for (int j = 0; j < 16; j++) {
            f16x8 bf = *(const f16x8*)&Bs[brow0 + j * 16 * 72 + bko];
            acc[0][j] = __builtin_amdgcn_mfma_f32_16x16x32_f16(a0, bf, acc[0][j], 0, 0, 0);
            acc[1][j] = __builtin_amdgcn_mfma_f32_16x16x32_f16(a1, bf, acc[1][j], 0, 0, 0);
        }
    }
    __syncthreads();   // xns visible to all (and LDS reads done)

    // epilogue: rowmax over 256 cols, exp, store
    float* outp = phi + ((size_t)bh * TT + t0) * MM;
#pragma unroll
    for (int i = 0; i < 2; i++) {
#pragma unroll
        for (int r = 0; r < 4; r++) {
            float mx = acc[i][0][r];
#pragma unroll
            for (int j = 1; j < 16; j++) mx = fmaxf(mx, acc[i][j][r]);
            mx = fmaxf(mx, __shfl_xor(mx, 1, 64));
            mx = fmaxf(mx, __shfl_xor(mx, 2, 64));
            mx = fmaxf(mx, __shfl_xor(mx, 4, 64));
            mx = fmaxf(mx, __shfl_xor(mx, 8, 64));
            const int row = w * 32 + i * 16 + (lane >> 4) * 4 + r;
            const float base = -mx - 0.5f * xns[row];
            float* orow = outp + (size_t)row * MM + (lane & 15);
#pragma unroll
            for (int j = 0; j < 16; j++)
                orow[j * 16] = (__expf(acc[i][j][r] + base) + FEPS) * 0.0625f;
        }
    }
}

// ---------------------------------------------------------------------------
// KV partial tiled GEMM: per block [64 m x 64 dk] over a 512-long t-chunk.
// ---------------------------------------------------------------------------
__global__ __launch_bounds__(256) void kv_partial(const float* __restrict__ phiK,
                                                  const float* __restrict__ V,
                                                  float* __restrict__ KVp)
{
    const int bh = blockIdx.y;
    const int b = bh >> 4, h = bh & 15;
    const int mt = blockIdx.x & 3;          // m-tile (64 wide)
    const int split = blockIdx.x >> 2;      // 0..7, 512 t each
    const int m0 = mt * 64;
    const int tid = threadIdx.x;
    const int tx = tid & 15;    // dk, 4 each
    const int ty = tid >> 4;    // m, 4 each

    __shared__ float Ps[32][68];
    __shared__ float Vs[32][68];

    float acc[4][4];
#pragma unroll
    for (int i = 0; i < 4; i++)
#pragma unroll
        for (int j = 0; j < 4; j++) acc[i][j] = 0.f;
    float ks0 = 0.f, ks1 = 0.f, ks2 = 0.f, ks3 = 0.f;

    const size_t pbase = (size_t)bh * TT * MM + m0;
    const size_t vbase = (size_t)b * TT * DD + h * DK;

    const int lt = tid >> 3;
    const int lc = (tid & 7) * 8;

    const int tend = split * 512 + 512;
    for (int t0 = split * 512; t0 < tend; t0 += 32) {
        const float* prow = phiK + pbase + (size_t)(t0 + lt) * MM + lc;
        const float* vrow = V + vbase + (size_t)(t0 + lt) * DD + lc;
        float4 p0 = *(const float4*)(prow);
        float4 p1 = *(const float4*)(prow + 4);
        float4 v0 = *(const float4*)(vrow);
        float4 v1 = *(const float4*)(vrow + 4);
        *(float4*)&Ps[lt][lc]     = p0;
        *(float4*)&Ps[lt][lc + 4] = p1;
        *(float4*)&Vs[lt][lc]     = v0;
        *(float4*)&Vs[lt][lc + 4] = v1;
        __syncthreads();
#pragma unroll
        for (int k = 0; k < 32; k++) {
            float4 a4 = *(const float4*)&Ps[k][ty * 4];
            float4 b4 = *(const float4*)&Vs[k][tx * 4];
            ks0 += a4.x; ks1 += a4.y; ks2 += a4.z; ks3 += a4.w;
            acc[0][0] += a4.x * b4.x; acc[0][1] += a4.x * b4.y;
            acc[0][2] += a4.x * b4.z; acc[0][3] += a4.x * b4.w;
            acc[1][0] += a4.y * b4.x; acc[1][1] += a4.y * b4.y;
            acc[1][2] += a4.y * b4.z; acc[1][3] += a4.y * b4.w;
            acc[2][0] += a4.z * b4.x; acc[2][1] += a4.z * b4.y;
            acc[2][2] += a4.z * b4.z; acc[2][3] += a4.z * b4.w;
            acc[3][0] += a4.w * b4.x; acc[3][1] += a4.w * b4.y;
            acc[3][2] += a4.w * b4.z; acc[3][3] += a4.w * b4.w;
        }
        __syncthreads();
    }

    float ksv[4] = {ks0, ks1, ks2, ks3};
    float* o = KVp + (((size_t)split * 32 + bh) * MM + m0) * 68;
#pragma unroll
    for (int i = 0; i < 4; i++) {
        float* orow = o + (size_t)(ty * 4 + i) * 68 + tx * 4;
        orow[0] = acc[i][0]; orow[1] = acc[i][1];
        orow[2] = acc[i][2]; orow[3] = acc[i][3];
        if (tx == 0) o[(size_t)(ty * 4 + i) * 68 + 64] = ksv[i];
    }
}

__global__ __launch_bounds__(256) void kv_reduce(const float* __restrict__ KVp,
                                                 float* __restrict__ KVf)
{
    int idx = blockIdx.x * 256 + threadIdx.x;   // 32*256*68 = 557056 exact
    float s = 0.f;
    for (int sp = 0; sp < 8; sp++) s += KVp[(size_t)sp * 32 * MM * 68 + idx];
    KVf[idx] = s;
}

// ---------------------------------------------------------------------------
// Output heads (register-tiled GEMM): per block [128 t x 64 dd].
// Epilogue writes hi/lo fp16 split of merged directly (out-GEMM A-operand).
// ---------------------------------------------------------------------------
__global__ __launch_bounds__(256) void attn_out(const float* __restrict__ phiQ,
                                                const float* __restrict__ KVf,
                                                unsigned short* __restrict__ mout)
{
    const int bh = blockIdx.y, b = bh >> 4, h = bh & 15;
    const int t0 = blockIdx.x * 128;
    const int tid = threadIdx.x;
    const int tx = tid & 15;      // dd quad
    const int ty = tid >> 4;      // t octet

    __shared__ float QsT[64][132];
    __shared__ float KVc[64][68];

    float acc[8][4];
    float den[8];
#pragma unroll
    for (int i = 0; i < 8; i++) {
        den[i] = 0.f;
#pragma unroll
        for (int j = 0; j < 4; j++) acc[i][j] = 0.f;
    }

    const float* Pq = phiQ + ((size_t)bh * TT + t0) * MM;
    const float* Kv = KVf + (size_t)bh * MM * 68;

    for (int m0 = 0; m0 < MM; m0 += 64) {
#pragma unroll
        for (int i = 0; i < 4; i++) {
            int s = tid + i * 256;
            int r = s >> 4, q = (s & 15) * 4;
            *(float4*)&KVc[r][q] = *(const float4*)(Kv + (size_t)(m0 + r) * 68 + q);
        }
        if (tid < 64) KVc[tid][64] = Kv[(size_t)(m0 + tid) * 68 + 64];
#pragma unroll
        for (int i = 0; i < 8; i++) {
            int s = tid + i * 256;
            int t = s >> 4, mq = (s & 15) * 4;
            float4 v = *(const float4*)(Pq + (size_t)t * MM + m0 + mq);
            QsT[mq + 0][t] = v.x; QsT[mq + 1][t] = v.y;
            QsT[mq + 2][t] = v.z; QsT[mq + 3][t] = v.w;
        }
        __syncthreads();
#pragma unroll 4
        for (int k = 0; k < 64; k++) {
            float a[8];
            *(float4*)&a[0] = *(const float4*)&QsT[k][ty * 8];
            *(float4*)&a[4] = *(const float4*)&QsT[k][ty * 8 + 4];
            float4 b4 = *(const float4*)&KVc[k][tx * 4];
            float km = KVc[k][64];
#pragma unroll
            for (int i = 0; i < 8; i++) {
                den[i]    += a[i] * km;
                acc[i][0] += a[i] * b4.x;
                acc[i][1] += a[i] * b4.y;
                acc[i][2] += a[i] * b4.z;
                acc[i][3] += a[i] * b4.w;
            }
        }
        __syncthreads();
    }

    unsigned short* Mh = mout + ((size_t)b * TT + t0) * 2048 + h * DK;
#pragma unroll
    for (int i = 0; i < 8; i++) {
        int t = ty * 8 + i;
        float dinv = 1.f / (den[i] + FEPS);
        float o[4];
        o[0] = acc[i][0] * dinv; o[1] = acc[i][1] * dinv;
        o[2] = acc[i][2] * dinv; o[3] = acc[i][3] * dinv;
        union { _Float16 h[4]; uint2 u; } hv, lv;
#pragma unroll
        for (int j = 0; j < 4; j++) {
            hv.h[j] = (_Float16)o[j];
            lv.h[j] = (_Float16)(o[j] - (float)hv.h[j]);
        }
        *(uint2*)(Mh + (size_t)t * 2048 + tx * 4)        = hv.u;
        *(uint2*)(Mh + (size_t)t * 2048 + 1024 + tx * 4) = lv.u;
    }
}

// ---------------------------------------------------------------------------
extern "C" void kernel_launch(void* const* d_in, const int* in_sizes, int n_in,
                              void* d_out, int out_size, void* d_ws, size_t ws_size,
                              hipStream_t stream)
{
    (void)in_sizes; (void)n_in; (void)out_size; (void)ws_size;
    const float* x    = (const float*)d_in[0];
    const float* Wq   = (const float*)d_in[1];
    const float* Wk   = (const float*)d_in[2];
    const float* Wv   = (const float*)d_in[3];
    const float* Wo   = (const float*)d_in[4];
    const float* bo   = (const float*)d_in[5];
    const float* proj = (const float*)d_in[6];
    float* out = (float*)d_out;

    float* ws  = (float*)d_ws;
    float* Qs  = ws;                          // 8388608 floats
    float* Ks  = Qs + 8388608ull;             // 8388608
    float* Vb  = Ks + 8388608ull;             // 8388608
    float* phi = Vb + 8388608ull;             // 33554432 (phiK then phiQ)
    float* KVp = phi + 33554432ull;           // 8*32*256*68 = 4456448
    float* KVf = KVp + 4456448ull;            // 32*256*68 = 557056

    // fp16 aliases (lifetime-disjoint with their hosts):
    unsigned short* x_hl = (unsigned short*)phi;  // dead once favor writes phi
    unsigned short* wqkv = (unsigned short*)KVp;  // dead before kv_partial writes
    unsigned short* wo_h = (unsigned short*)Qs;   // written after Qs is dead
    unsigned short* m_hl = (unsigned short*)Ks;   // written after Ks is dead

    dim3 gthr(256);

    split_w3h<<<dim3(3072), gthr, 0, stream>>>(Wq, Wk, Wv, wqkv);
    split_hl <<<dim3(8192), gthr, 0, stream>>>(x, x_hl);
    mfma_gemm3<<<dim3(24, 64), gthr, 0, stream>>>(
        x_hl, wqkv, wqkv + 1048576, wqkv + 2097152,
        Qs, Ks, Vb, nullptr, 0.125f, 0.125f, 1.0f);

    favor_mfma<<<dim3(32, 32), gthr, 0, stream>>>(Ks, proj, phi);        // phiK (clobbers x_hl, dead)
    kv_partial <<<dim3(32, 32), gthr, 0, stream>>>(phi, Vb, KVp);        // clobbers wqkv (dead)
    kv_reduce  <<<dim3(2176),   gthr, 0, stream>>>(KVp, KVf);
    favor_mfma<<<dim3(32, 32), gthr, 0, stream>>>(Qs, proj, phi);        // phiQ (Qs dead after)
    split_w3h  <<<dim3(1024),   gthr, 0, stream>>>(Wo, Wo, Wo, wo_h);    // into Qs region
    attn_out   <<<dim3(32, 32), gthr, 0, stream>>>(phi, KVf, m_hl);      // writes Ks region

    mfma_gemm3<<<dim3(8, 64), gthr, 0, stream>>>(
        m_hl, wo_h, wo_h, wo_h, out, out, out, bo, 1.0f, 1.0f, 1.0f);
}

// Round 9
// 486.049 us; speedup vs baseline: 3.5477x; 1.0766x over previous
//
#include <hip/hip_runtime.h>
#include <hip/hip_bf16.h>
#include <math.h>

// Problem constants (FavorPlusAttention): B=2, T=4096, d=1024, h=16, dk=64, m=256
#define BB 2
#define TT 4096
#define DD 1024
#define NH 16
#define DK 64
#define MM 256
#define BT (BB*TT)        // 8192 rows
#define FEPS 1e-6f

typedef _Float16 f16x8 __attribute__((ext_vector_type(8)));
using f32x4 = __attribute__((ext_vector_type(4))) float;

#define GL2LDS16(g, l) __builtin_amdgcn_global_load_lds( \
    (const __attribute__((address_space(1))) void*)(g), \
    (__attribute__((address_space(3))) void*)(l), 16, 0, 0)

static __device__ __forceinline__ unsigned short f16bits(_Float16 v) {
    union { _Float16 f; unsigned short u; } c; c.f = v; return c.u;
}

// ---------------------------------------------------------------------------
// hi/lo fp16 split: src [rows][1024] fp32 -> dst [rows][2048] f16 = [hi|lo]
// ---------------------------------------------------------------------------
__global__ __launch_bounds__(256) void split_hl(const float* __restrict__ src,
                                                unsigned short* __restrict__ dst)
{
    const int r = blockIdx.x;
    const int c = threadIdx.x * 4;
    float4 v = *(const float4*)(src + (size_t)r * 1024 + c);
    float f[4] = {v.x, v.y, v.z, v.w};
    union { _Float16 h[4]; uint2 u; } hv, lv;
#pragma unroll
    for (int i = 0; i < 4; i++) {
        hv.h[i] = (_Float16)f[i];
        lv.h[i] = (_Float16)(f[i] - (float)hv.h[i]);
    }
    unsigned short* d = dst + (size_t)r * 2048;
    *(uint2*)(d + c)        = hv.u;
    *(uint2*)(d + 1024 + c) = lv.u;
}

// hi-only fp16 weight cast: 3 weights -> [3][1024][1024] f16 (B-operand).
__global__ __launch_bounds__(256) void split_w3h(const float* __restrict__ W0,
                                                 const float* __restrict__ W1,
                                                 const float* __restrict__ W2,
                                                 unsigned short* __restrict__ dst)
{
    const int r = blockIdx.x;            // 0..3071
    const int wi = r >> 10, rr = r & 1023;
    const float* W = (wi == 0) ? W0 : (wi == 1) ? W1 : W2;
    const int c = threadIdx.x * 4;
    float4 v = *(const float4*)(W + (size_t)rr * 1024 + c);
    float f[4] = {v.x, v.y, v.z, v.w};
    union { _Float16 h[4]; uint2 u; } hv;
#pragma unroll
    for (int i = 0; i < 4; i++) hv.h[i] = (_Float16)f[i];
    *(uint2*)(dst + (size_t)r * 1024 + c) = hv.u;
}

// ---------------------------------------------------------------------------
// Split-fp16 MFMA GEMM (m97 structure): C = scale*(A@B^T) (+bias)
// A: [8192][2048] f16 [hi|lo], B: [1024][1024] f16 hi. K' = 2048 (Ahi*Bhi,
// Alo*Bhi). 128x128 tile, BK=32, 4 waves, 4x4 of 16x16x32 f16 MFMA.
// ---------------------------------------------------------------------------
__global__ __launch_bounds__(256) void mfma_gemm3(
    const unsigned short* __restrict__ A,
    const unsigned short* __restrict__ B0, const unsigned short* __restrict__ B1,
    const unsigned short* __restrict__ B2,
    float* __restrict__ C0, float* __restrict__ C1, float* __restrict__ C2,
    const float* __restrict__ bias,
    float sc0, float sc1, float sc2)
{
    const int which = blockIdx.x >> 3;
    const int nb = blockIdx.x & 7;
    const int row0 = blockIdx.y * 128;
    const int col0 = nb * 128;
    const unsigned short* Bp = (which == 0) ? B0 : (which == 1) ? B1 : B2;
    float* Cp = (which == 0) ? C0 : (which == 1) ? C1 : C2;
    const float scl = (which == 0) ? sc0 : (which == 1) ? sc1 : sc2;

    __shared__ unsigned short As[128 * 32];   // 8 KB, [row][k] row-major
    __shared__ unsigned short Bs[128 * 32];

    const int tid = threadIdx.x;
    const int w = tid >> 6, lane = tid & 63;
    const int wm = w & 1, wn = w >> 1;

    f32x4 acc[4][4];
#pragma unroll
    for (int i = 0; i < 4; i++)
#pragma unroll
        for (int j = 0; j < 4; j++) acc[i][j] = (f32x4){0.f, 0.f, 0.f, 0.f};

    const int sl0 = (w * 2 + 0) * 64 + lane;
    const int sl1 = (w * 2 + 1) * 64 + lane;
    const size_t aoff0 = (size_t)(row0 + (sl0 >> 2)) * 2048 + (sl0 & 3) * 8;
    const size_t aoff1 = (size_t)(row0 + (sl1 >> 2)) * 2048 + (sl1 & 3) * 8;
    const size_t boff0 = (size_t)(col0 + (sl0 >> 2)) * 1024 + (sl0 & 3) * 8;
    const size_t boff1 = (size_t)(col0 + (sl1 >> 2)) * 1024 + (sl1 & 3) * 8;
    unsigned short* lA0 = &As[(w * 2 + 0) * 64 * 8];
    unsigned short* lA1 = &As[(w * 2 + 1) * 64 * 8];
    unsigned short* lB0 = &Bs[(w * 2 + 0) * 64 * 8];
    unsigned short* lB1 = &Bs[(w * 2 + 1) * 64 * 8];

    const int aFr = (wm * 64 + (lane & 15)) * 32 + (lane >> 4) * 8;
    const int bFr = (wn * 64 + (lane & 15)) * 32 + (lane >> 4) * 8;

    for (int it = 0; it < 64; it++) {
        const int kk = (it & 31) * 32;
        const int ka = kk + ((it >> 5) ? 1024 : 0);   // A: hi then lo
        GL2LDS16(A + aoff0 + ka, lA0);
        GL2LDS16(A + aoff1 + ka, lA1);
        GL2LDS16(Bp + boff0 + kk, lB0);
        GL2LDS16(Bp + boff1 + kk, lB1);
        __syncthreads();
        f16x8 af[4], bfr[4];
#pragma unroll
        for (int i = 0; i < 4; i++) {
            af[i]  = *(const f16x8*)&As[aFr + i * 512];
            bfr[i] = *(const f16x8*)&Bs[bFr + i * 512];
        }
#pragma unroll
        for (int i = 0; i < 4; i++)
#pragma unroll
            for (int j = 0; j < 4; j++)
                acc[i][j] = __builtin_amdgcn_mfma_f32_16x16x32_f16(
                    af[i], bfr[j], acc[i][j], 0, 0, 0);
        __syncthreads();
    }

    // epilogue: C/D layout col = lane&15, row = (lane>>4)*4 + reg  [m89]
    float bv[4];
#pragma unroll
    for (int j = 0; j < 4; j++) {
        int gcol = col0 + wn * 64 + j * 16 + (lane & 15);
        bv[j] = bias ? bias[gcol] : 0.f;
    }
#pragma unroll
    for (int i = 0; i < 4; i++) {
        const int grow = row0 + wm * 64 + i * 16 + (lane >> 4) * 4;
#pragma unroll
        for (int r = 0; r < 4; r++) {
            float* Crow = Cp + (size_t)(grow + r) * 1024;
#pragma unroll
            for (int j = 0; j < 4; j++) {
                int gcol = col0 + wn * 64 + j * 16 + (lane & 15);
                Crow[gcol] = acc[i][j][r] * scl + bv[j];
            }
        }
    }
}

// ---------------------------------------------------------------------------
// FAVOR+ features via MFMA (phiK only): per block one bh, [128 t x 256 m].
// Unchanged from round 6/8 (verified).
// ---------------------------------------------------------------------------
__global__ __launch_bounds__(256) void favor_mfma(const float* __restrict__ X,
                                                  const float* __restrict__ proj,
                                                  float* __restrict__ phi)
{
    const int bh = blockIdx.y;
    const int b = bh >> 4, h = bh & 15;
    const int t0 = blockIdx.x * 128;
    const int tid = threadIdx.x;
    const int w = tid >> 6, lane = tid & 63;

    __shared__ unsigned short Aq[128 * 136];   // [t][k'], hi 0..63, lo 64..127
    __shared__ unsigned short Bs[256 * 72];    // [m][k] hi only
    __shared__ float xns[128];

    const float* Xb = X + ((size_t)b * TT + t0) * DD + h * DK;
    const float* Pj = proj + (size_t)h * MM * DK;

#pragma unroll
    for (int i = 0; i < 8; i++) {
        int s = tid + i * 256;
        int r = s >> 4, q = (s & 15) * 4;
        float4 v = *(const float4*)(Xb + (size_t)r * DD + q);
        float f[4] = {v.x, v.y, v.z, v.w};
        union { _Float16 h[4]; uint2 u; } hv, lv;
#pragma unroll
        for (int e = 0; e < 4; e++) {
            hv.h[e] = (_Float16)f[e];
            lv.h[e] = (_Float16)(f[e] - (float)hv.h[e]);
        }
        *(uint2*)&Aq[r * 136 + q]      = hv.u;
        *(uint2*)&Aq[r * 136 + 64 + q] = lv.u;
    }
#pragma unroll
    for (int i = 0; i < 16; i++) {
        int s = tid + i * 256;
        int r = s >> 4, q = (s & 15) * 4;
        float4 v = *(const float4*)(Pj + (size_t)r * DK + q);
        float f[4] = {v.x, v.y, v.z, v.w};
        union { _Float16 h[4]; uint2 u; } hv;
#pragma unroll
        for (int e = 0; e < 4; e++) hv.h[e] = (_Float16)f[e];
        *(uint2*)&Bs[r * 72 + q] = hv.u;
    }
    __syncthreads();

    if (tid < 128) {
        const unsigned short* ar = &Aq[tid * 136];
        float s = 0.f;
#pragma unroll 8
        for (int k = 0; k < 64; k++) {
            float qv = (float)(*(const _Float16*)&ar[k])
                     + (float)(*(const _Float16*)&ar[64 + k]);
            s += qv * qv;
        }
        xns[tid] = s;
    }

    f32x4 acc[2][16];
#pragma unroll
    for (int i = 0; i < 2; i++)
#pragma unroll
        for (int j = 0; j < 16; j++) acc[i][j] = (f32x4){0.f, 0.f, 0.f, 0.f};

    const int arow0 = (w * 32 + (lane & 15)) * 136 + (lane >> 4) * 8;
    const int brow0 = (lane & 15) * 72 + (lane >> 4) * 8;
#pragma unroll
    for (int ks = 0; ks < 4; ks++) {
        f16x8 a0 = *(const f16x8*)&Aq[arow0 + ks * 32];
        f16x8 a1 = *(const f16x8*)&Aq[arow0 + 16 * 136 + ks * 32];
        const int bko = (ks & 1) * 32;
#pragma unroll
        for (int j = 0; j < 16; j++) {
            f16x8 bf = *(const f16x8*)&Bs[brow0 + j * 16 * 72 + bko];
            acc[0][j] = __builtin_amdgcn_mfma_f32_16x16x32_f16(a0, bf, acc[0][j], 0, 0, 0);
            acc[1][j] = __builtin_amdgcn_mfma_f32_16x16x32_f16(a1, bf, acc[1][j], 0, 0, 0);
        }
    }
    __syncthreads();

    float* outp = phi + ((size_t)bh * TT + t0) * MM;
#pragma unroll
    for (int i = 0; i < 2; i++) {
#pragma unroll
        for (int r = 0; r < 4; r++) {
            float mx = acc[i][0][r];
#pragma unroll
            for (int j = 1; j < 16; j++) mx = fmaxf(mx, acc[i][j][r]);
            mx = fmaxf(mx, __shfl_xor(mx, 1, 64));
            mx = fmaxf(mx, __shfl_xor(mx, 2, 64));
            mx = fmaxf(mx, __shfl_xor(mx, 4, 64));
            mx = fmaxf(mx, __shfl_xor(mx, 8, 64));
            const int row = w * 32 + i * 16 + (lane >> 4) * 4 + r;
            const float base = -mx - 0.5f * xns[row];
            float* orow = outp + (size_t)row * MM + (lane & 15);
#pragma unroll
            for (int j = 0; j < 16; j++)
                orow[j * 16] = (__expf(acc[i][j][r] + base) + FEPS) * 0.0625f;
        }
    }
}

// ---------------------------------------------------------------------------
// KV partial tiled GEMM: per block [64 m x 64 dk] over a 512-long t-chunk.
// (unchanged)
// ---------------------------------------------------------------------------
__global__ __launch_bounds__(256) void kv_partial(const float* __restrict__ phiK,
                                                  const float* __restrict__ V,
                                                  float* __restrict__ KVp)
{
    const int bh = blockIdx.y;
    const int b = bh >> 4, h = bh & 15;
    const int mt = blockIdx.x & 3;          // m-tile (64 wide)
    const int split = blockIdx.x >> 2;      // 0..7, 512 t each
    const int m0 = mt * 64;
    const int tid = threadIdx.x;
    const int tx = tid & 15;    // dk, 4 each
    const int ty = tid >> 4;    // m, 4 each

    __shared__ float Ps[32][68];
    __shared__ float Vs[32][68];

    float acc[4][4];
#pragma unroll
    for (int i = 0; i < 4; i++)
#pragma unroll
        for (int j = 0; j < 4; j++) acc[i][j] = 0.f;
    float ks0 = 0.f, ks1 = 0.f, ks2 = 0.f, ks3 = 0.f;

    const size_t pbase = (size_t)bh * TT * MM + m0;
    const size_t vbase = (size_t)b * TT * DD + h * DK;

    const int lt = tid >> 3;
    const int lc = (tid & 7) * 8;

    const int tend = split * 512 + 512;
    for (int t0 = split * 512; t0 < tend; t0 += 32) {
        const float* prow = phiK + pbase + (size_t)(t0 + lt) * MM + lc;
        const float* vrow = V + vbase + (size_t)(t0 + lt) * DD + lc;
        float4 p0 = *(const float4*)(prow);
        float4 p1 = *(const float4*)(prow + 4);
        float4 v0 = *(const float4*)(vrow);
        float4 v1 = *(const float4*)(vrow + 4);
        *(float4*)&Ps[lt][lc]     = p0;
        *(float4*)&Ps[lt][lc + 4] = p1;
        *(float4*)&Vs[lt][lc]     = v0;
        *(float4*)&Vs[lt][lc + 4] = v1;
        __syncthreads();
#pragma unroll
        for (int k = 0; k < 32; k++) {
            float4 a4 = *(const float4*)&Ps[k][ty * 4];
            float4 b4 = *(const float4*)&Vs[k][tx * 4];
            ks0 += a4.x; ks1 += a4.y; ks2 += a4.z; ks3 += a4.w;
            acc[0][0] += a4.x * b4.x; acc[0][1] += a4.x * b4.y;
            acc[0][2] += a4.x * b4.z; acc[0][3] += a4.x * b4.w;
            acc[1][0] += a4.y * b4.x; acc[1][1] += a4.y * b4.y;
            acc[1][2] += a4.y * b4.z; acc[1][3] += a4.y * b4.w;
            acc[2][0] += a4.z * b4.x; acc[2][1] += a4.z * b4.y;
            acc[2][2] += a4.z * b4.z; acc[2][3] += a4.z * b4.w;
            acc[3][0] += a4.w * b4.x; acc[3][1] += a4.w * b4.y;
            acc[3][2] += a4.w * b4.z; acc[3][3] += a4.w * b4.w;
        }
        __syncthreads();
    }

    float ksv[4] = {ks0, ks1, ks2, ks3};
    float* o = KVp + (((size_t)split * 32 + bh) * MM + m0) * 68;
#pragma unroll
    for (int i = 0; i < 4; i++) {
        float* orow = o + (size_t)(ty * 4 + i) * 68 + tx * 4;
        orow[0] = acc[i][0]; orow[1] = acc[i][1];
        orow[2] = acc[i][2]; orow[3] = acc[i][3];
        if (tx == 0) o[(size_t)(ty * 4 + i) * 68 + 64] = ksv[i];
    }
}

// ---------------------------------------------------------------------------
// kv_reduce v2: sum 8 split partials and emit KV^T directly as fp16 hi/lo
// planes for the fused attention kernel's B-operand:
// KVt16[bh][plane(2)][c(68)][m(256)], c: 0..63 = dk, 64 = Ksum, 65..67 = 0.
// ---------------------------------------------------------------------------
__global__ __launch_bounds__(256) void kv_reduce(const float* __restrict__ KVp,
                                                 unsigned short* __restrict__ KVt16)
{
    int idx = blockIdx.x * 256 + threadIdx.x;   // 32*256*68 = 557056 exact
    float s = 0.f;
    for (int sp = 0; sp < 8; sp++) s += KVp[(size_t)sp * 32 * MM * 68 + idx];
    int bh = idx / 17408;
    int rm = idx - bh * 17408;
    int m = rm / 68;
    int c = rm - m * 68;
    _Float16 hv = (_Float16)0.f, lv = (_Float16)0.f;
    if (c <= 64) {
        hv = (_Float16)s;
        lv = (_Float16)(s - (float)hv);
    }
    KVt16[((size_t)(bh * 2 + 0) * 68 + c) * 256 + m] = f16bits(hv);
    KVt16[((size_t)(bh * 2 + 1) * 68 + c) * 256 + m] = f16bits(lv);
}

// ---------------------------------------------------------------------------
// FUSED favor(Q) + attn_out: per block one bh, 128 t rows.
// Phase A: phiQ = favor(Q) via split-fp16 MFMA (identical math to favor_mfma),
//          phi kept in registers (C-layout) — never materialized to HBM.
// Phase B: for each 64-m chunk: phi chunk -> LDS in A-layout fp16 hi/lo;
//          KV^T chunk (from KVt16) -> LDS [80 rows: 64 dk + Ksum@64 + 0-pad];
//          3-seg MFMA (phihi*KVhi + philo*KVhi + phihi*KVlo) accumulates
//          num (j=0..3) and den (j=4, via Ksum column).
// Epilogue: den broadcast via shfl, out = num/(den+eps) written as fp16 hi/lo
//          merged (out-GEMM A-operand).
// Dynamic LDS 72192 B: phase A {Xq[128*136]u16, Pp[256*72]u16, xns[128]f32},
// phase B reuses {Aq = Xq region, Bt[80*136]u16 = Pp region}.
// grid (32 t-tiles, 32 bh), 256 thr, 2 blocks/CU.
// ---------------------------------------------------------------------------
__global__ __launch_bounds__(256, 2) void favor_attn(
    const float* __restrict__ X,
    const float* __restrict__ proj,
    const unsigned short* __restrict__ KVt16,
    unsigned short* __restrict__ mout)
{
    extern __shared__ char smem[];
    unsigned short* Xq = (unsigned short*)smem;             // [128][136]
    unsigned short* Pp = (unsigned short*)(smem + 34816);   // [256][72]
    float* xns         = (float*)(smem + 71680);            // [128]
    unsigned short* Aq = Xq;                                // phase B alias
    unsigned short* Bt = Pp;                                // [80][136]

    const int bh = blockIdx.y;
    const int b = bh >> 4, h = bh & 15;
    const int t0 = blockIdx.x * 128;
    const int tid = threadIdx.x;
    const int w = tid >> 6, lane = tid & 63;

    const float* Xb = X + ((size_t)b * TT + t0) * DD + h * DK;
    const float* Pj = proj + (size_t)h * MM * DK;

    // ---- phase A: stage X (hi/lo) + proj (hi) ----
#pragma unroll
    for (int i = 0; i < 8; i++) {
        int s = tid + i * 256;
        int r = s >> 4, q = (s & 15) * 4;
        float4 v = *(const float4*)(Xb + (size_t)r * DD + q);
        float f[4] = {v.x, v.y, v.z, v.w};
        union { _Float16 h[4]; uint2 u; } hv, lv;
#pragma unroll
        for (int e = 0; e < 4; e++) {
            hv.h[e] = (_Float16)f[e];
            lv.h[e] = (_Float16)(f[e] - (float)hv.h[e]);
        }
        *(uint2*)&Xq[r * 136 + q]      = hv.u;
        *(uint2*)&Xq[r * 136 + 64 + q] = lv.u;
    }
#pragma unroll
    for (int i = 0; i < 16; i++) {
        int s = tid + i * 256;
        int r = s >> 4, q = (s & 15) * 4;
        float4 v = *(const float4*)(Pj + (size_t)r * DK + q);
        float f[4] = {v.x, v.y, v.z, v.w};
        union { _Float16 h[4]; uint2 u; } hv;
#pragma unroll
        for (int e = 0; e < 4; e++) hv.h[e] = (_Float16)f[e];
        *(uint2*)&Pp[r * 72 + q] = hv.u;
    }
    __syncthreads();

    if (tid < 128) {
        const unsigned short* ar = &Xq[tid * 136];
        float s = 0.f;
#pragma unroll 8
        for (int k = 0; k < 64; k++) {
            float qv = (float)(*(const _Float16*)&ar[k])
                     + (float)(*(const _Float16*)&ar[64 + k]);
            s += qv * qv;
        }
        xns[tid] = s;
    }

    f32x4 facc[2][16];
#pragma unroll
    for (int i = 0; i < 2; i++)
#pragma unroll
        for (int j = 0; j < 16; j++) facc[i][j] = (f32x4){0.f, 0.f, 0.f, 0.f};

    const int arow0 = (w * 32 + (lane & 15)) * 136 + (lane >> 4) * 8;
    const int brow0 = (lane & 15) * 72 + (lane >> 4) * 8;
#pragma unroll
    for (int ks = 0; ks < 4; ks++) {
        f16x8 a0 = *(const f16x8*)&Xq[arow0 + ks * 32];
        f16x8 a1 = *(const f16x8*)&Xq[arow0 + 16 * 136 + ks * 32];
        const int bko = (ks & 1) * 32;
#pragma unroll
        for (int j = 0; j < 16; j++) {
            f16x8 bf = *(const f16x8*)&Pp[brow0 + j * 16 * 72 + bko];
            facc[0][j] = __builtin_amdgcn_mfma_f32_16x16x32_f16(a0, bf, facc[0][j], 0, 0, 0);
            facc[1][j] = __builtin_amdgcn_mfma_f32_16x16x32_f16(a1, bf, facc[1][j], 0, 0, 0);
        }
    }
    __syncthreads();   // phase A LDS reads done; xns visible

    // rowmax -> base per (i, r)
    float base[2][4];
#pragma unroll
    for (int i = 0; i < 2; i++) {
#pragma unroll
        for (int r = 0; r < 4; r++) {
            float mx = facc[i][0][r];
#pragma unroll
            for (int j = 1; j < 16; j++) mx = fmaxf(mx, facc[i][j][r]);
            mx = fmaxf(mx, __shfl_xor(mx, 1, 64));
            mx = fmaxf(mx, __shfl_xor(mx, 2, 64));
            mx = fmaxf(mx, __shfl_xor(mx, 4, 64));
            mx = fmaxf(mx, __shfl_xor(mx, 8, 64));
            const int row = w * 32 + i * 16 + (lane >> 4) * 4 + r;
            base[i][r] = -mx - 0.5f * xns[row];
        }
    }

    // ---- phase B: chunked phi->Aq + KV^T->Bt + 3-seg MFMA ----
    f32x4 aacc[2][5];
#pragma unroll
    for (int i = 0; i < 2; i++)
#pragma unroll
        for (int j = 0; j < 5; j++) aacc[i][j] = (f32x4){0.f, 0.f, 0.f, 0.f};

    const int aFr = (w * 32 + (lane & 15)) * 136 + (lane >> 4) * 8;
    const int bFr = (lane & 15) * 136 + (lane >> 4) * 8;

#pragma unroll
    for (int c = 0; c < 4; c++) {
        // write phi chunk (hi|lo) to Aq in A-layout [t][mc]
#pragma unroll
        for (int i = 0; i < 2; i++) {
#pragma unroll
            for (int jj = 0; jj < 4; jj++) {
#pragma unroll
                for (int r = 0; r < 4; r++) {
                    float ph = (__expf(facc[i][c * 4 + jj][r] + base[i][r]) + FEPS) * 0.0625f;
                    _Float16 hv = (_Float16)ph;
                    _Float16 lv = (_Float16)(ph - (float)hv);
                    int row = w * 32 + i * 16 + (lane >> 4) * 4 + r;
                    int mc = jj * 16 + (lane & 15);
                    Aq[row * 136 + mc]      = f16bits(hv);
                    Aq[row * 136 + 64 + mc] = f16bits(lv);
                }
            }
        }
        // stage Bt chunk: rows 0..67 from KVt16, 68..79 zero
#pragma unroll
        for (int i = 0; i < 10; i++) {
            int s = tid + i * 256;           // 2560 = 2 planes * 80 rows * 16 quads
            int p = (s >= 1280) ? 1 : 0;
            int s2 = s - p * 1280;
            int r = s2 >> 4, q = (s2 & 15) * 4;
            uint2 v = make_uint2(0u, 0u);
            if (r < 68)
                v = *(const uint2*)(KVt16 + ((size_t)(bh * 2 + p) * 68 + r) * 256 + c * 64 + q);
            *(uint2*)&Bt[r * 136 + p * 64 + q] = v;
        }
        __syncthreads();
#pragma unroll
        for (int ks = 0; ks < 2; ks++) {
            f16x8 ah0 = *(const f16x8*)&Aq[aFr + ks * 32];
            f16x8 ah1 = *(const f16x8*)&Aq[aFr + 16 * 136 + ks * 32];
            f16x8 al0 = *(const f16x8*)&Aq[aFr + 64 + ks * 32];
            f16x8 al1 = *(const f16x8*)&Aq[aFr + 16 * 136 + 64 + ks * 32];
#pragma unroll
            for (int j = 0; j < 5; j++) {
                f16x8 bh_ = *(const f16x8*)&Bt[bFr + j * 16 * 136 + ks * 32];
                f16x8 bl_ = *(const f16x8*)&Bt[bFr + j * 16 * 136 + 64 + ks * 32];
                aacc[0][j] = __builtin_amdgcn_mfma_f32_16x16x32_f16(ah0, bl_, aacc[0][j], 0, 0, 0);
                aacc[0][j] = __builtin_amdgcn_mfma_f32_16x16x32_f16(al0, bh_, aacc[0][j], 0, 0, 0);
                aacc[0][j] = __builtin_amdgcn_mfma_f32_16x16x32_f16(ah0, bh_, aacc[0][j], 0, 0, 0);
                aacc[1][j] = __builtin_amdgcn_mfma_f32_16x16x32_f16(ah1, bl_, aacc[1][j], 0, 0, 0);
                aacc[1][j] = __builtin_amdgcn_mfma_f32_16x16x32_f16(al1, bh_, aacc[1][j], 0, 0, 0);
                aacc[1][j] = __builtin_amdgcn_mfma_f32_16x16x32_f16(ah1, bh_, aacc[1][j], 0, 0, 0);
            }
        }
        __syncthreads();
    }

    // ---- epilogue: out = num/(den+eps), write merged fp16 hi/lo ----
    unsigned short* Mh = mout + ((size_t)b * TT + t0) * 2048 + h * DK;
#pragma unroll
    for (int i = 0; i < 2; i++) {
#pragma unroll
        for (int r = 0; r < 4; r++) {
            float den = aacc[i][4][r];                 // col 64 lives at lane&15==0
            den = __shfl(den, lane & 48, 64);          // broadcast to the 16-lane group
            float dinv = 1.f / (den + FEPS);
            int trow = w * 32 + i * 16 + (lane >> 4) * 4 + r;
#pragma unroll
            for (int j = 0; j < 4; j++) {
                float o = aacc[i][j][r] * dinv;
                _Float16 hv = (_Float16)o;
                _Float16 lv = (_Float16)(o - (float)hv);
                Mh[(size_t)trow * 2048 + j * 16 + (lane & 15)]        = f16bits(hv);
                Mh[(size_t)trow * 2048 + 1024 + j * 16 + (lane & 15)] = f16bits(lv);
            }
        }
    }
}

// ---------------------------------------------------------------------------
extern "C" void kernel_launch(void* const* d_in, const int* in_sizes, int n_in,
                              void* d_out, int out_size, void* d_ws, size_t ws_size,
                              hipStream_t stream)
{
    (void)in_sizes; (void)n_in; (void)out_size; (void)ws_size;
    const float* x    = (const float*)d_in[0];
    const float* Wq   = (const float*)d_in[1];
    const float* Wk   = (const float*)d_in[2];
    const float* Wv   = (const float*)d_in[3];
    const float* Wo   = (const float*)d_in[4];
    const float* bo   = (const float*)d_in[5];
    const float* proj = (const float*)d_in[6];
    float* out = (float*)d_out;

    float* ws  = (float*)d_ws;
    float* Qs  = ws;                          // 8388608 floats
    float* Ks  = Qs + 8388608ull;             // 8388608
    float* Vb  = Ks + 8388608ull;             // 8388608
    float* phi = Vb + 8388608ull;             // 33554432 (phiK only now)
    float* KVp = phi + 33554432ull;           // 8*32*256*68 = 4456448

    // aliases (lifetime-disjoint with their hosts):
    unsigned short* x_hl  = (unsigned short*)phi;  // dead once favor writes phi
    unsigned short* wqkv  = (unsigned short*)KVp;  // dead before kv_partial writes
    unsigned short* wo_h  = (unsigned short*)Qs;   // written after Qs is dead
    unsigned short* m_hl  = (unsigned short*)Ks;   // written after Ks is dead
    unsigned short* KVt16 = (unsigned short*)phi;  // written after phiK is dead

    dim3 gthr(256);

    split_w3h<<<dim3(3072), gthr, 0, stream>>>(Wq, Wk, Wv, wqkv);
    split_hl <<<dim3(8192), gthr, 0, stream>>>(x, x_hl);
    mfma_gemm3<<<dim3(24, 64), gthr, 0, stream>>>(
        x_hl, wqkv, wqkv + 1048576, wqkv + 2097152,
        Qs, Ks, Vb, nullptr, 0.125f, 0.125f, 1.0f);

    favor_mfma<<<dim3(32, 32), gthr, 0, stream>>>(Ks, proj, phi);      // phiK (clobbers x_hl, dead)
    kv_partial<<<dim3(32, 32), gthr, 0, stream>>>(phi, Vb, KVp);       // clobbers wqkv (dead)
    kv_reduce <<<dim3(2176),   gthr, 0, stream>>>(KVp, KVt16);         // KVt16 over dead phiK
    favor_attn<<<dim3(32, 32), gthr, 72192, stream>>>(Qs, proj, KVt16, m_hl);  // Qs dead after
    split_w3h <<<dim3(1024),   gthr, 0, stream>>>(Wo, Wo, Wo, wo_h);   // into Qs region

    mfma_gemm3<<<dim3(8, 64), gthr, 0, stream>>>(
        m_hl, wo_h, wo_h, wo_h, out, out, out, bo, 1.0f, 1.0f, 1.0f);
}